// Round 17
// baseline (136.718 us; speedup 1.0000x reference)
//
#include <hip/hip_runtime.h>
#include <math.h>

#define H 64
#define NXCD 8
#define CH 2048
#define CH2 8192
#define CAP 4096

typedef __attribute__((ext_vector_type(8))) short short8;
typedef __attribute__((ext_vector_type(4))) float f32x4;

__device__ inline ushort f2bf(float f) {
    union { float f; unsigned u; } v;
    v.f = f;
    unsigned r = v.u + 0x7FFFu + ((v.u >> 16) & 1u);
    return (ushort)(r >> 16);
}

// ================= FAST PATH =================

// ---------- Stage 0: bucket-level histogram via LDS ----------
__global__ __launch_bounds__(256) void k_count(const int* __restrict__ dst,
                                               unsigned* __restrict__ bcnt, int E, int NB) {
    __shared__ unsigned lc[1024];
    for (int j = threadIdx.x; j < NB; j += 256) lc[j] = 0;
    __syncthreads();
    int i = blockIdx.x * blockDim.x + threadIdx.x;
    int st = gridDim.x * blockDim.x;
    int E4 = E >> 2;
    const int4* d4 = (const int4*)dst;
    for (int k = i; k < E4; k += st) {
        int4 v = d4[k];
        atomicAdd(&lc[v.x >> 8], 1u);
        atomicAdd(&lc[v.y >> 8], 1u);
        atomicAdd(&lc[v.z >> 8], 1u);
        atomicAdd(&lc[v.w >> 8], 1u);
    }
    for (int k = (E4 << 2) + i; k < E; k += st) atomicAdd(&lc[dst[k] >> 8], 1u);
    __syncthreads();
    for (int j = threadIdx.x; j < NB; j += 256)
        if (lc[j]) atomicAdd(&bcnt[j], lc[j]);
}

// ---------- Stage 1: single-block scan of bucket counts ----------
__global__ __launch_bounds__(1024) void k_scan_small(const unsigned* __restrict__ bcnt,
                                                     unsigned* __restrict__ bstart2,
                                                     unsigned* __restrict__ bcur2,
                                                     unsigned* __restrict__ bmeta,
                                                     int NB, int partsize, int E) {
    __shared__ unsigned wsum[16];
    __shared__ unsigned sex[1025];
    int i = threadIdx.x;
    unsigned v = (i < NB) ? bcnt[i] : 0u;
    int lane = i & 63, w = i >> 6;
    unsigned x = v;
#pragma unroll
    for (int off = 1; off < 64; off <<= 1) {
        unsigned y = __shfl_up(x, off, 64);
        if (lane >= off) x += y;
    }
    if (lane == 63) wsum[w] = x;
    __syncthreads();
    if (i < 16) {
        unsigned s = wsum[i];
#pragma unroll
        for (int off = 1; off < 16; off <<= 1) {
            unsigned y = __shfl_up(s, off, 16);
            if ((i & 15) >= off) s += y;
        }
        wsum[i] = s;
    }
    __syncthreads();
    unsigned wbase = (w > 0) ? wsum[w - 1] : 0u;
    unsigned excl = wbase + x - v;
    sex[i] = excl;
    if (i == 0) sex[1024] = (unsigned)E;
    __syncthreads();
    if (i <= NB) bstart2[i] = sex[i];
    if (i < NB) bcur2[i] = sex[i];
    if (i <= NXCD) {
        int bidx = (i * partsize) >> 8;
        if (bidx > NB) bidx = NB;
        bmeta[i] = sex[bidx];
        if (i < NXCD) bmeta[16 + i] = sex[bidx];
    }
}

// ---------- Stage 2a: edges -> part-binned u64 (d:17|src:17|ebf16) ----------
__global__ __launch_bounds__(256) void k_bin(const int* __restrict__ dst,
                                             const int* __restrict__ src,
                                             const float* __restrict__ t,
                                             unsigned* __restrict__ bcur,
                                             unsigned long long* __restrict__ bin1,
                                             int E, int partsize) {
    __shared__ unsigned lcnt[NXCD];
    __shared__ unsigned lofs[NXCD];
    int e0 = blockIdx.x * CH;
    int e1 = min(e0 + CH, E);
    if (threadIdx.x < NXCD) lcnt[threadIdx.x] = 0;
    __syncthreads();
    for (int i = e0 + threadIdx.x; i < e1; i += 256) {
        int d = dst[i];
        int p = 0;
#pragma unroll
        for (int k = 1; k < NXCD; ++k) p += (d >= k * partsize);
        atomicAdd(&lcnt[p], 1u);
    }
    __syncthreads();
    if (threadIdx.x < NXCD)
        lofs[threadIdx.x] = atomicAdd(&bcur[threadIdx.x], lcnt[threadIdx.x]);
    __syncthreads();
    const float inv = 1.0f / (0.5f + 1e-8f);
    for (int i = e0 + threadIdx.x; i < e1; i += 256) {
        int d = dst[i];
        int p = 0;
#pragma unroll
        for (int k = 1; k < NXCD; ++k) p += (d >= k * partsize);
        unsigned u = atomicAdd(&lofs[p], 1u);
        unsigned eb = f2bf(__expf(t[i] * inv));
        bin1[u] = ((unsigned long long)d << 33) | ((unsigned long long)src[i] << 16)
                | (unsigned long long)eb;
    }
}

// ---------- Stage 2b: part bin -> bucket bin ----------
__global__ __launch_bounds__(256) void k_bin2(const unsigned* __restrict__ bmeta,
                                              const unsigned long long* __restrict__ bin1,
                                              unsigned* __restrict__ bcur2,
                                              unsigned long long* __restrict__ bin2,
                                              int partsize) {
    __shared__ unsigned lcnt[64];
    __shared__ unsigned lofs[64];
    int p = blockIdx.y;
    int b0 = (int)bmeta[p], b1 = (int)bmeta[p + 1];
    int bloc0 = (p * partsize) >> 8;
    int stridec = gridDim.x * CH2;
    for (int c0 = b0 + blockIdx.x * CH2; c0 < b1; c0 += stridec) {
        int c1 = min(c0 + CH2, b1);
        if (threadIdx.x < 64) lcnt[threadIdx.x] = 0;
        __syncthreads();
        for (int i = c0 + threadIdx.x; i < c1; i += 256) {
            int d = (int)(bin1[i] >> 33);
            atomicAdd(&lcnt[(d >> 8) - bloc0], 1u);
        }
        __syncthreads();
        if (threadIdx.x < 64) {
            unsigned cn = lcnt[threadIdx.x];
            lofs[threadIdx.x] = cn ? atomicAdd(&bcur2[bloc0 + threadIdx.x], cn) : 0u;
        }
        __syncthreads();
        for (int i = c0 + threadIdx.x; i < c1; i += 256) {
            unsigned long long u = bin1[i];
            int d = (int)(u >> 33);
            unsigned pos = atomicAdd(&lofs[(d >> 8) - bloc0], 1u);
            bin2[pos] = u;
        }
        __syncthreads();
    }
}

// ---------- Stage 2c: bucket bin -> CSR payload + base[] via LDS assembly ----------
__global__ __launch_bounds__(256) void k_fine2(const unsigned* __restrict__ bstart2,
                                               const unsigned long long* __restrict__ bin2,
                                               int2* __restrict__ payload,
                                               unsigned* __restrict__ base, int N, int E) {
    __shared__ int2 sPay[CAP];
    __shared__ unsigned lcnt[256];
    __shared__ unsigned lrel[256];
    __shared__ unsigned wsum[4];
    int b = blockIdx.x;
    int d0 = b << 8;
    int d1 = min(d0 + 256, N);
    int nd = d1 - d0;
    unsigned g0 = bstart2[b];
    unsigned g1 = bstart2[b + 1];
    int cnt = (int)(g1 - g0);
    int tid = threadIdx.x;
    lcnt[tid] = 0;
    __syncthreads();
    for (int i = (int)g0 + tid; i < (int)g1; i += 256)
        atomicAdd(&lcnt[(int)(bin2[i] >> 33) - d0], 1u);
    __syncthreads();
    unsigned v = lcnt[tid];
    int lane = tid & 63, w = tid >> 6;
    unsigned x = v;
#pragma unroll
    for (int off = 1; off < 64; off <<= 1) {
        unsigned y = __shfl_up(x, off, 64);
        if (lane >= off) x += y;
    }
    if (lane == 63) wsum[w] = x;
    __syncthreads();
    if (tid == 0) {
        unsigned s = 0;
#pragma unroll
        for (int k = 0; k < 4; ++k) { unsigned tq = wsum[k]; wsum[k] = s; s += tq; }
    }
    __syncthreads();
    unsigned excl = wsum[w] + x - v;
    lrel[tid] = excl;
    if (tid < nd) base[d0 + tid] = g0 + excl;
    if (b == gridDim.x - 1 && tid == 0) base[N] = (unsigned)E;
    __syncthreads();
    lcnt[tid] = excl;
    __syncthreads();
    for (int i = (int)g0 + tid; i < (int)g1; i += 256) {
        unsigned long long u = bin2[i];
        int d = (int)(u >> 33);
        int s = (int)((u >> 16) & 0x1FFFF);
        float e = __uint_as_float((unsigned)(u & 0xFFFFu) << 16);
        unsigned lpos = atomicAdd(&lcnt[d - d0], 1u);
        int2 pv = make_int2(s, __float_as_int(e));
        if (lpos < CAP) sPay[lpos] = pv;
        else payload[g0 + lpos] = pv;  // spill: correctness only
    }
    __syncthreads();
    int wn = min(cnt, CAP);
    for (int j = tid; j < wn; j += 256) payload[g0 + j] = sPay[j];
}

// ---------- Pre-transform: y(bf16) = x @ W^T via MFMA; block 0 zeroes bcnt ----------
__global__ __launch_bounds__(256) void k_xform_mfma(const float* __restrict__ x,
                                                    const float* __restrict__ W,
                                                    ushort* __restrict__ y, int M,
                                                    unsigned* __restrict__ bcnt, int NB) {
    if (bcnt != nullptr && blockIdx.x == 0) {
        for (int j = threadIdx.x; j < NB; j += 256) bcnt[j] = 0u;
    }
    int wid = (blockIdx.x * blockDim.x + threadIdx.x) >> 6;
    int lane = threadIdx.x & 63;
    int n0 = wid * 16;
    if (n0 >= M) return;
    int r = lane & 15, g = lane >> 4;

    short8 bfrag[4][2];
#pragma unroll
    for (int ct = 0; ct < 4; ++ct) {
#pragma unroll
        for (int kh = 0; kh < 2; ++kh) {
            const float* wp = &W[(size_t)(ct * 16 + r) * 64 + kh * 32 + g * 8];
            float4 w0 = *(const float4*)wp;
            float4 w1 = *(const float4*)(wp + 4);
            short8 bf;
            bf[0] = (short)f2bf(w0.x); bf[1] = (short)f2bf(w0.y);
            bf[2] = (short)f2bf(w0.z); bf[3] = (short)f2bf(w0.w);
            bf[4] = (short)f2bf(w1.x); bf[5] = (short)f2bf(w1.y);
            bf[6] = (short)f2bf(w1.z); bf[7] = (short)f2bf(w1.w);
            bfrag[ct][kh] = bf;
        }
    }
    int xr = n0 + r;
    if (xr >= M) xr = M - 1;
    const float* xp = &x[(size_t)xr * 64 + g * 8];
    short8 afrag[2];
#pragma unroll
    for (int kh = 0; kh < 2; ++kh) {
        float4 a0 = *(const float4*)(xp + kh * 32);
        float4 a1 = *(const float4*)(xp + kh * 32 + 4);
        short8 af;
        af[0] = (short)f2bf(a0.x); af[1] = (short)f2bf(a0.y);
        af[2] = (short)f2bf(a0.z); af[3] = (short)f2bf(a0.w);
        af[4] = (short)f2bf(a1.x); af[5] = (short)f2bf(a1.y);
        af[6] = (short)f2bf(a1.z); af[7] = (short)f2bf(a1.w);
        afrag[kh] = af;
    }
#pragma unroll
    for (int ct = 0; ct < 4; ++ct) {
        f32x4 acc = {0.f, 0.f, 0.f, 0.f};
        acc = __builtin_amdgcn_mfma_f32_16x16x32_bf16(afrag[0], bfrag[ct][0], acc, 0, 0, 0);
        acc = __builtin_amdgcn_mfma_f32_16x16x32_bf16(afrag[1], bfrag[ct][1], acc, 0, 0, 0);
#pragma unroll
        for (int q = 0; q < 4; ++q) {
            int row = n0 + g * 4 + q;
            if (row < M) y[(size_t)row * 64 + ct * 16 + r] = f2bf(acc[q]);
        }
    }
}

// ---------- Pass 3: weighted gather, 8 dests/wave, 8 lanes/dest, uint4 loads ----------
// Doubles per-wave MLP (32 outstanding row loads) and halves load instructions vs R10.
__global__ __launch_bounds__(256) void k_gather8(const unsigned* __restrict__ base,
                                                 const long long* __restrict__ payload,
                                                 const uint4* __restrict__ y4,
                                                 float* __restrict__ out, int N) {
    int tid = blockIdx.x * blockDim.x + threadIdx.x;
    int lane = threadIdx.x & 63;
    int g = lane >> 3, f = lane & 7;
    int d = (tid >> 6) * 8 + g;
    if (d >= N) return;
    unsigned r0 = base[d], r1 = base[d + 1];
    int deg = (int)(r1 - r0);
    float acc[8] = {0.f, 0.f, 0.f, 0.f, 0.f, 0.f, 0.f, 0.f};
    float ssum = 0.f;
    for (int it = 0; it < deg; it += 4) {
        float e[4];
        int s[4];
#pragma unroll
        for (int k2 = 0; k2 < 4; ++k2) {
            // memory-safe overread: payload region is followed by bin2 region in ws
            long long pl = __builtin_nontemporal_load(&payload[r0 + it + k2]);
            bool ok = (it + k2) < deg;
            e[k2] = ok ? __int_as_float((int)(pl >> 32)) : 0.f;
            s[k2] = ok ? (int)(pl & 0xFFFFFFFFll) : 0;
            ssum += e[k2];
        }
        uint4 v[4];
#pragma unroll
        for (int k2 = 0; k2 < 4; ++k2) v[k2] = y4[(size_t)s[k2] * 8 + f];
#pragma unroll
        for (int k2 = 0; k2 < 4; ++k2) {
            acc[0] = fmaf(e[k2], __uint_as_float(v[k2].x << 16), acc[0]);
            acc[1] = fmaf(e[k2], __uint_as_float(v[k2].x & 0xFFFF0000u), acc[1]);
            acc[2] = fmaf(e[k2], __uint_as_float(v[k2].y << 16), acc[2]);
            acc[3] = fmaf(e[k2], __uint_as_float(v[k2].y & 0xFFFF0000u), acc[3]);
            acc[4] = fmaf(e[k2], __uint_as_float(v[k2].z << 16), acc[4]);
            acc[5] = fmaf(e[k2], __uint_as_float(v[k2].z & 0xFFFF0000u), acc[5]);
            acc[6] = fmaf(e[k2], __uint_as_float(v[k2].w << 16), acc[6]);
            acc[7] = fmaf(e[k2], __uint_as_float(v[k2].w & 0xFFFF0000u), acc[7]);
        }
    }
    float rs = 1.0f / (ssum + 1e-16f);
    f32x4 o0 = {acc[0] * rs, acc[1] * rs, acc[2] * rs, acc[3] * rs};
    f32x4 o1 = {acc[4] * rs, acc[5] * rs, acc[6] * rs, acc[7] * rs};
    float* op = &out[(size_t)d * H + f * 8];
    __builtin_nontemporal_store(o0, (f32x4*)op);
    __builtin_nontemporal_store(o1, (f32x4*)(op + 4));
}

// ---------- R10 gather (16 lanes/dest, uint2) kept for fallback path ----------
__global__ __launch_bounds__(256) void k_gather4(const unsigned* __restrict__ base,
                                                 const long long* __restrict__ payload,
                                                 const uint2* __restrict__ y2,
                                                 float* __restrict__ out, int N) {
    int tid = blockIdx.x * blockDim.x + threadIdx.x;
    int lane = threadIdx.x & 63;
    int g = lane >> 4, f = lane & 15;
    int d = (tid >> 6) * 4 + g;
    if (d >= N) return;
    unsigned r0 = base[d], r1 = base[d + 1];
    int deg = (int)(r1 - r0);
    float acc0 = 0.f, acc1 = 0.f, acc2 = 0.f, acc3 = 0.f, ssum = 0.f;
    for (int it = 0; it < deg; it += 4) {
        float e[4];
        int s[4];
#pragma unroll
        for (int k2 = 0; k2 < 4; ++k2) {
            long long pl = __builtin_nontemporal_load(&payload[r0 + it + k2]);
            bool ok = (it + k2) < deg;
            e[k2] = ok ? __int_as_float((int)(pl >> 32)) : 0.f;
            s[k2] = ok ? (int)(pl & 0xFFFFFFFFll) : 0;
            ssum += e[k2];
        }
        uint2 v[4];
#pragma unroll
        for (int k2 = 0; k2 < 4; ++k2) v[k2] = y2[(size_t)s[k2] * 16 + f];
#pragma unroll
        for (int k2 = 0; k2 < 4; ++k2) {
            acc0 = fmaf(e[k2], __uint_as_float(v[k2].x << 16), acc0);
            acc1 = fmaf(e[k2], __uint_as_float(v[k2].x & 0xFFFF0000u), acc1);
            acc2 = fmaf(e[k2], __uint_as_float(v[k2].y << 16), acc2);
            acc3 = fmaf(e[k2], __uint_as_float(v[k2].y & 0xFFFF0000u), acc3);
        }
    }
    float rs = 1.0f / (ssum + 1e-16f);
    f32x4 o = {acc0 * rs, acc1 * rs, acc2 * rs, acc3 * rs};
    __builtin_nontemporal_store(o, (f32x4*)&out[(size_t)d * H + f * 4]);
}

// ================= FALLBACK PATH (R10-proven) =================

__global__ void k_hist(const int* __restrict__ dst, unsigned* __restrict__ cnt, int E) {
    int i = blockIdx.x * blockDim.x + threadIdx.x;
    int st = gridDim.x * blockDim.x;
    int E4 = E >> 2;
    const int4* d4 = (const int4*)dst;
    for (int k = i; k < E4; k += st) {
        int4 v = d4[k];
        atomicAdd(&cnt[v.x], 1u);
        atomicAdd(&cnt[v.y], 1u);
        atomicAdd(&cnt[v.z], 1u);
        atomicAdd(&cnt[v.w], 1u);
    }
    for (int k = (E4 << 2) + i; k < E; k += st) atomicAdd(&cnt[dst[k]], 1u);
}

__global__ __launch_bounds__(1024) void k_scanA(const unsigned* __restrict__ cnt,
                                                unsigned* __restrict__ base,
                                                unsigned* __restrict__ bsum, int N) {
    __shared__ unsigned wsum[16];
    int i = blockIdx.x * 1024 + threadIdx.x;
    unsigned v = (i < N) ? cnt[i] : 0u;
    int lane = threadIdx.x & 63, w = threadIdx.x >> 6;
    unsigned x = v;
#pragma unroll
    for (int off = 1; off < 64; off <<= 1) {
        unsigned y = __shfl_up(x, off, 64);
        if (lane >= off) x += y;
    }
    if (lane == 63) wsum[w] = x;
    __syncthreads();
    if (threadIdx.x < 16) {
        unsigned s = wsum[threadIdx.x];
#pragma unroll
        for (int off = 1; off < 16; off <<= 1) {
            unsigned y = __shfl_up(s, off, 16);
            if ((threadIdx.x & 15) >= off) s += y;
        }
        wsum[threadIdx.x] = s;
    }
    __syncthreads();
    unsigned wbase = (w > 0) ? wsum[w - 1] : 0u;
    if (i < N) base[i] = wbase + x - v;
    if (threadIdx.x == 1023) bsum[blockIdx.x] = wsum[15];
}

__global__ __launch_bounds__(1024) void k_scanB(const unsigned* __restrict__ bsum,
                                                unsigned* __restrict__ boff, int nb) {
    __shared__ unsigned wsum[16];
    int i = threadIdx.x;
    unsigned v = (i < nb) ? bsum[i] : 0u;
    int lane = i & 63, w = i >> 6;
    unsigned x = v;
#pragma unroll
    for (int off = 1; off < 64; off <<= 1) {
        unsigned y = __shfl_up(x, off, 64);
        if (lane >= off) x += y;
    }
    if (lane == 63) wsum[w] = x;
    __syncthreads();
    if (i < 16) {
        unsigned s = wsum[i];
#pragma unroll
        for (int off = 1; off < 16; off <<= 1) {
            unsigned y = __shfl_up(s, off, 16);
            if ((i & 15) >= off) s += y;
        }
        wsum[i] = s;
    }
    __syncthreads();
    unsigned wbase = (w > 0) ? wsum[w - 1] : 0u;
    if (i < nb) boff[i] = wbase + x - v;
}

__global__ void k_scanC(unsigned* __restrict__ base, unsigned* __restrict__ cursor,
                        const unsigned* __restrict__ boff, int N, int E) {
    int i = blockIdx.x * blockDim.x + threadIdx.x;
    int st = gridDim.x * blockDim.x;
    for (; i < N; i += st) {
        unsigned b = base[i] + boff[i >> 10];
        base[i] = b;
        cursor[i] = b;
    }
    if (blockIdx.x == 0 && threadIdx.x == 0) base[N] = (unsigned)E;
}

__global__ void k_permute_part(const int* __restrict__ dst, const int* __restrict__ src,
                               const float* __restrict__ t, unsigned* __restrict__ cursor,
                               int2* __restrict__ payload, int E, int N) {
    const float inv = 1.0f / (0.5f + 1e-8f);
    int part = blockIdx.x & (NXCD - 1);
    int nslice = gridDim.x >> 3;
    int sblk = blockIdx.x >> 3;
    int lo = (int)((long long)part * N / NXCD);
    int hi = (int)((long long)(part + 1) * N / NXCD);
    int e0 = (int)((long long)sblk * E / nslice);
    int e1 = (int)((long long)(sblk + 1) * E / nslice);
    for (int i = e0 + threadIdx.x; i < e1; i += blockDim.x) {
        int d = dst[i];
        if (d >= lo && d < hi) {
            unsigned pos = atomicAdd(&cursor[d], 1u);
            float e = __expf(t[i] * inv);
            payload[pos] = make_int2(src[i], __float_as_int(e));
        }
    }
}

__global__ void k_permute_pack(const int* __restrict__ dst, const int* __restrict__ src,
                               const float* __restrict__ t, unsigned* __restrict__ cursor,
                               int2* __restrict__ payload, int E) {
    const float inv = 1.0f / (0.5f + 1e-8f);
    int i = blockIdx.x * blockDim.x + threadIdx.x;
    int st = gridDim.x * blockDim.x;
    for (; i < E; i += st) {
        unsigned pos = atomicAdd(&cursor[dst[i]], 1u);
        float e = __expf(t[i] * inv);
        payload[pos] = make_int2(src[i], __float_as_int(e));
    }
}

__global__ __launch_bounds__(256) void k_gather_fb(const unsigned* __restrict__ base,
                                                   const int2* __restrict__ payload,
                                                   const float* __restrict__ x_src,
                                                   const float* __restrict__ W,
                                                   float* __restrict__ out, int N) {
    __shared__ float wt[H * H];
    for (int idx = threadIdx.x; idx < H * H; idx += blockDim.x) {
        int j = idx >> 6, k = idx & 63;
        wt[k * H + j] = W[idx];
    }
    __syncthreads();
    int lane = threadIdx.x & 63;
    int wid = (blockIdx.x * blockDim.x + threadIdx.x) >> 6;
    int nw = (gridDim.x * blockDim.x) >> 6;
    for (int d = wid; d < N; d += nw) {
        unsigned r0 = base[d], r1 = base[d + 1];
        int deg = (int)(r1 - r0);
        float acc = 0.0f, ssum = 0.0f;
        for (int c = 0; c < deg; c += 64) {
            int j = c + lane;
            int cd = min(64, deg - c);
            float e = 0.0f;
            int sidx = 0;
            if (j < deg) {
                int2 p = payload[r0 + j];
                sidx = p.x;
                e = __int_as_float(p.y);
            }
            float cs = e;
#pragma unroll
            for (int off = 32; off >= 1; off >>= 1) cs += __shfl_xor(cs, off, 64);
            ssum += cs;
            for (int q = 0; q < cd; q += 8) {
                float a[8];
                int sv[8];
                float v[8];
#pragma unroll
                for (int u = 0; u < 8; ++u) {
                    a[u] = __shfl(e, q + u, 64);
                    sv[u] = __shfl(sidx, q + u, 64);
                }
#pragma unroll
                for (int u = 0; u < 8; ++u) v[u] = x_src[(size_t)sv[u] * H + lane];
#pragma unroll
                for (int u = 0; u < 8; ++u) acc = fmaf(a[u], v[u], acc);
            }
        }
        acc *= 1.0f / (ssum + 1e-16f);
        float o = 0.0f;
#pragma unroll
        for (int k = 0; k < H; ++k) o = fmaf(__shfl(acc, k, 64), wt[k * H + lane], o);
        out[(size_t)d * H + lane] = o;
    }
}

extern "C" void kernel_launch(void* const* d_in, const int* in_sizes, int n_in,
                              void* d_out, int out_size, void* d_ws, size_t ws_size,
                              hipStream_t stream) {
    const float* x_src = (const float*)d_in[0];
    const float* W = (const float*)d_in[2];
    const int* edge_index = (const int*)d_in[3];
    const float* t = (const float*)d_in[4];

    int E = in_sizes[4];
    int N = in_sizes[1] / H;  // N_DST
    int M = in_sizes[0] / H;  // N_SRC
    const int* src = edge_index;
    const int* dst = edge_index + E;

    unsigned* base = (unsigned*)d_ws;
    unsigned* cursor = base + (size_t)N + 1;
    unsigned* bsum = cursor + N;
    unsigned* boff = bsum + 1024;
    unsigned* bmeta = boff + 1024;
    unsigned* bcnt = bmeta + 32;
    unsigned* bstart2 = bcnt + 1024;
    unsigned* bcur2 = bstart2 + 1056;
    size_t head_u32 = (size_t)(2 * N + 1) + 1024 + 1024 + 32 + 1024 + 1056 + 1056;
    size_t pay_off = (head_u32 * 4 + 15) & ~(size_t)15;
    int2* payload = (int2*)((char*)d_ws + pay_off);
    unsigned long long* bin1 = (unsigned long long*)payload;  // alias
    size_t b2_off = (pay_off + (size_t)E * 8 + 15) & ~(size_t)15;
    unsigned long long* bin2 = (unsigned long long*)((char*)d_ws + b2_off);
    size_t y_off = b2_off + (size_t)E * 8;
    ushort* y = (ushort*)((char*)d_ws + y_off);

    bool have_y_small = (ws_size >= pay_off + (size_t)E * 8 + (size_t)M * H * 2 + 32);
    bool have_full = (ws_size >= y_off + (size_t)M * H * 2);
    bool packable = (M < (1 << 17)) && (N < (1 << 17));

    int nb = (N + 1023) / 1024;
    int ps0 = (N + NXCD - 1) / NXCD;
    int partsize = (ps0 + 255) & ~255;
    int NB = (N + 255) >> 8;

    int blocks_e = (E + 255) / 256;
    if (blocks_e > 2048) blocks_e = 2048;

    if (have_full && packable && NB <= 1024) {
        int xblocks = ((M + 15) / 16 * 64 + 255) / 256;
        k_xform_mfma<<<xblocks, 256, 0, stream>>>(x_src, W, y, M, bcnt, NB);
        k_count<<<1024, 256, 0, stream>>>(dst, bcnt, E, NB);
        k_scan_small<<<1, 1024, 0, stream>>>(bcnt, bstart2, bcur2, bmeta, NB, partsize, E);
        int nbin = (E + CH - 1) / CH;
        k_bin<<<nbin, 256, 0, stream>>>(dst, src, t, bmeta + 16, bin1, E, partsize);
        int nb2 = (E / NXCD + CH2 - 1) / CH2 + 1;
        dim3 g2(nb2, NXCD);
        k_bin2<<<g2, 256, 0, stream>>>(bmeta, bin1, bcur2, bin2, partsize);
        k_fine2<<<NB, 256, 0, stream>>>(bstart2, bin2, payload, base, N, E);
        int gblocks = (N + 31) / 32;  // 4 waves/block, 8 dests/wave
        k_gather8<<<gblocks, 256, 0, stream>>>(base, (const long long*)payload,
                                               (const uint4*)y, (float*)d_out, N);
    } else if (have_y_small) {
        ushort* y2p = (ushort*)((char*)d_ws + pay_off + (size_t)E * 8);
        hipMemsetAsync(cursor, 0, (size_t)N * sizeof(unsigned), stream);
        k_hist<<<1024, 256, 0, stream>>>(dst, cursor, E);
        k_scanA<<<nb, 1024, 0, stream>>>(cursor, base, bsum, N);
        k_scanB<<<1, 1024, 0, stream>>>(bsum, boff, nb);
        k_scanC<<<512, 256, 0, stream>>>(base, cursor, boff, N, E);
        int xblocks = ((M + 15) / 16 * 64 + 255) / 256;
        k_xform_mfma<<<xblocks, 256, 0, stream>>>(x_src, W, y2p, M, nullptr, 0);
        k_permute_part<<<2048, 256, 0, stream>>>(dst, src, t, cursor, payload, E, N);
        int gblocks = (N + 15) / 16;
        k_gather4<<<gblocks, 256, 0, stream>>>(base, (const long long*)payload,
                                               (const uint2*)y2p, (float*)d_out, N);
    } else {
        hipMemsetAsync(cursor, 0, (size_t)N * sizeof(unsigned), stream);
        k_hist<<<1024, 256, 0, stream>>>(dst, cursor, E);
        k_scanA<<<nb, 1024, 0, stream>>>(cursor, base, bsum, N);
        k_scanB<<<1, 1024, 0, stream>>>(bsum, boff, nb);
        k_scanC<<<512, 256, 0, stream>>>(base, cursor, boff, N, E);
        k_permute_pack<<<blocks_e, 256, 0, stream>>>(dst, src, t, cursor, payload, E);
        k_gather_fb<<<4096, 256, 0, stream>>>(base, payload, x_src, W, (float*)d_out, N);
    }
}

// Round 18
// 123.731 us; speedup vs baseline: 1.1050x; 1.1050x over previous
//
#include <hip/hip_runtime.h>
#include <math.h>

#define H 64
#define NXCD 8
#define CH 2048
#define CH2 8192
#define CAP 4096

typedef __attribute__((ext_vector_type(8))) short short8;
typedef __attribute__((ext_vector_type(4))) float f32x4;

__device__ inline ushort f2bf(float f) {
    union { float f; unsigned u; } v;
    v.f = f;
    unsigned r = v.u + 0x7FFFu + ((v.u >> 16) & 1u);
    return (ushort)(r >> 16);
}

// ================= FAST PATH =================

// ---------- Stage 0: bucket-level histogram via LDS ----------
__global__ __launch_bounds__(256) void k_count(const int* __restrict__ dst,
                                               unsigned* __restrict__ bcnt, int E, int NB) {
    __shared__ unsigned lc[1024];
    for (int j = threadIdx.x; j < NB; j += 256) lc[j] = 0;
    __syncthreads();
    int i = blockIdx.x * blockDim.x + threadIdx.x;
    int st = gridDim.x * blockDim.x;
    int E4 = E >> 2;
    const int4* d4 = (const int4*)dst;
    for (int k = i; k < E4; k += st) {
        int4 v = d4[k];
        atomicAdd(&lc[v.x >> 8], 1u);
        atomicAdd(&lc[v.y >> 8], 1u);
        atomicAdd(&lc[v.z >> 8], 1u);
        atomicAdd(&lc[v.w >> 8], 1u);
    }
    for (int k = (E4 << 2) + i; k < E; k += st) atomicAdd(&lc[dst[k] >> 8], 1u);
    __syncthreads();
    for (int j = threadIdx.x; j < NB; j += 256)
        if (lc[j]) atomicAdd(&bcnt[j], lc[j]);
}

// ---------- Stage 1: single-block scan of bucket counts ----------
__global__ __launch_bounds__(1024) void k_scan_small(const unsigned* __restrict__ bcnt,
                                                     unsigned* __restrict__ bstart2,
                                                     unsigned* __restrict__ bcur2,
                                                     unsigned* __restrict__ bmeta,
                                                     int NB, int partsize, int E) {
    __shared__ unsigned wsum[16];
    __shared__ unsigned sex[1025];
    int i = threadIdx.x;
    unsigned v = (i < NB) ? bcnt[i] : 0u;
    int lane = i & 63, w = i >> 6;
    unsigned x = v;
#pragma unroll
    for (int off = 1; off < 64; off <<= 1) {
        unsigned y = __shfl_up(x, off, 64);
        if (lane >= off) x += y;
    }
    if (lane == 63) wsum[w] = x;
    __syncthreads();
    if (i < 16) {
        unsigned s = wsum[i];
#pragma unroll
        for (int off = 1; off < 16; off <<= 1) {
            unsigned y = __shfl_up(s, off, 16);
            if ((i & 15) >= off) s += y;
        }
        wsum[i] = s;
    }
    __syncthreads();
    unsigned wbase = (w > 0) ? wsum[w - 1] : 0u;
    unsigned excl = wbase + x - v;
    sex[i] = excl;
    if (i == 0) sex[1024] = (unsigned)E;
    __syncthreads();
    if (i <= NB) bstart2[i] = sex[i];
    if (i < NB) bcur2[i] = sex[i];
    if (i <= NXCD) {
        int bidx = (i * partsize) >> 8;
        if (bidx > NB) bidx = NB;
        bmeta[i] = sex[bidx];
        if (i < NXCD) bmeta[16 + i] = sex[bidx];
    }
}

// ---------- Stage 2a: edges -> part-binned u64 (d:17|src:17|ebf16) ----------
__global__ __launch_bounds__(256) void k_bin(const int* __restrict__ dst,
                                             const int* __restrict__ src,
                                             const float* __restrict__ t,
                                             unsigned* __restrict__ bcur,
                                             unsigned long long* __restrict__ bin1,
                                             int E, int partsize) {
    __shared__ unsigned lcnt[NXCD];
    __shared__ unsigned lofs[NXCD];
    int e0 = blockIdx.x * CH;
    int e1 = min(e0 + CH, E);
    if (threadIdx.x < NXCD) lcnt[threadIdx.x] = 0;
    __syncthreads();
    for (int i = e0 + threadIdx.x; i < e1; i += 256) {
        int d = dst[i];
        int p = 0;
#pragma unroll
        for (int k = 1; k < NXCD; ++k) p += (d >= k * partsize);
        atomicAdd(&lcnt[p], 1u);
    }
    __syncthreads();
    if (threadIdx.x < NXCD)
        lofs[threadIdx.x] = atomicAdd(&bcur[threadIdx.x], lcnt[threadIdx.x]);
    __syncthreads();
    const float inv = 1.0f / (0.5f + 1e-8f);
    for (int i = e0 + threadIdx.x; i < e1; i += 256) {
        int d = dst[i];
        int p = 0;
#pragma unroll
        for (int k = 1; k < NXCD; ++k) p += (d >= k * partsize);
        unsigned u = atomicAdd(&lofs[p], 1u);
        unsigned eb = f2bf(__expf(t[i] * inv));
        bin1[u] = ((unsigned long long)d << 33) | ((unsigned long long)src[i] << 16)
                | (unsigned long long)eb;
    }
}

// ---------- Stage 2b: part bin -> bucket bin ----------
__global__ __launch_bounds__(256) void k_bin2(const unsigned* __restrict__ bmeta,
                                              const unsigned long long* __restrict__ bin1,
                                              unsigned* __restrict__ bcur2,
                                              unsigned long long* __restrict__ bin2,
                                              int partsize) {
    __shared__ unsigned lcnt[64];
    __shared__ unsigned lofs[64];
    int p = blockIdx.y;
    int b0 = (int)bmeta[p], b1 = (int)bmeta[p + 1];
    int bloc0 = (p * partsize) >> 8;
    int stridec = gridDim.x * CH2;
    for (int c0 = b0 + blockIdx.x * CH2; c0 < b1; c0 += stridec) {
        int c1 = min(c0 + CH2, b1);
        if (threadIdx.x < 64) lcnt[threadIdx.x] = 0;
        __syncthreads();
        for (int i = c0 + threadIdx.x; i < c1; i += 256) {
            int d = (int)(bin1[i] >> 33);
            atomicAdd(&lcnt[(d >> 8) - bloc0], 1u);
        }
        __syncthreads();
        if (threadIdx.x < 64) {
            unsigned cn = lcnt[threadIdx.x];
            lofs[threadIdx.x] = cn ? atomicAdd(&bcur2[bloc0 + threadIdx.x], cn) : 0u;
        }
        __syncthreads();
        for (int i = c0 + threadIdx.x; i < c1; i += 256) {
            unsigned long long u = bin1[i];
            int d = (int)(u >> 33);
            unsigned pos = atomicAdd(&lofs[(d >> 8) - bloc0], 1u);
            bin2[pos] = u;
        }
        __syncthreads();
    }
}

// ---------- Stage 2c (FUSED): bucket bin -> LDS CSR slab -> direct gather ----------
// One block per 256-dst bucket, 1024 threads (16 waves). Phase A assembles the
// bucket's CSR slab + local offsets in LDS (k_fine2-verified logic). Phase B
// gathers: 8 lanes/dst, payload entries read from LDS (8-lane broadcast),
// y rows from global, out written once. No payload/base global round-trip.
__global__ __launch_bounds__(1024) void k_fuse(const unsigned* __restrict__ bstart2,
                                               const unsigned long long* __restrict__ bin2,
                                               long long* __restrict__ spill,
                                               const uint4* __restrict__ y4,
                                               float* __restrict__ out, int N) {
    __shared__ long long sPay[CAP + 4];
    __shared__ unsigned lcnt[256];
    __shared__ unsigned lrel[257];
    __shared__ unsigned wsum[4];
    int b = blockIdx.x;
    int d0 = b << 8;
    int d1 = min(d0 + 256, N);
    int nd = d1 - d0;
    unsigned g0 = bstart2[b];
    unsigned g1 = bstart2[b + 1];
    int cnt = (int)(g1 - g0);
    int tid = threadIdx.x;
    if (tid < 256) lcnt[tid] = 0;
    __syncthreads();
    // Phase A1: count local dsts
    for (int i = (int)g0 + tid; i < (int)g1; i += 1024)
        atomicAdd(&lcnt[(int)(bin2[i] >> 33) - d0], 1u);
    __syncthreads();
    // Phase A2: exclusive scan of 256 counters (threads 0..255 = waves 0..3)
    if (tid < 256) {
        unsigned v = lcnt[tid];
        int lane = tid & 63, w = tid >> 6;
        unsigned x = v;
#pragma unroll
        for (int off = 1; off < 64; off <<= 1) {
            unsigned y = __shfl_up(x, off, 64);
            if (lane >= off) x += y;
        }
        if (lane == 63) wsum[w] = x;
        __syncthreads();
        if (tid == 0) {
            unsigned s = 0;
#pragma unroll
            for (int k = 0; k < 4; ++k) { unsigned tq = wsum[k]; wsum[k] = s; s += tq; }
        }
        __syncthreads();
        unsigned excl = wsum[w] + x - v;
        lrel[tid] = excl;
        lcnt[tid] = excl;  // running cursor
        if (tid == 0) lrel[256] = (unsigned)cnt;
    } else {
        __syncthreads();
        __syncthreads();
    }
    __syncthreads();
    // Phase A3: scatter entries into LDS slab (pack (e_f32:32 | src:32), payload layout)
    for (int i = (int)g0 + tid; i < (int)g1; i += 1024) {
        unsigned long long u = bin2[i];
        int d = (int)(u >> 33);
        int s = (int)((u >> 16) & 0x1FFFF);
        unsigned ef = (unsigned)(u & 0xFFFFu) << 16;
        unsigned lpos = atomicAdd(&lcnt[d - d0], 1u);
        long long pv = ((long long)(int)ef << 32) | (unsigned)s;
        if (lpos < CAP) sPay[lpos] = pv;
        else spill[g0 + lpos] = pv;  // statistically never; correctness only
    }
    __syncthreads();
    // Phase B: gather. 16 waves * 8 dst-slots/wave = 128 dsts per round, 2 rounds.
    int g = tid >> 3, f = tid & 7;
#pragma unroll
    for (int round = 0; round < 2; ++round) {
        int ld = round * 128 + g;
        if (ld >= nd) continue;
        int r0 = (int)lrel[ld];
        int r1 = (int)lrel[ld + 1];
        int deg = r1 - r0;
        float acc[8] = {0.f, 0.f, 0.f, 0.f, 0.f, 0.f, 0.f, 0.f};
        float ssum = 0.f;
        bool allLds = (r1 + 3 <= CAP);
        for (int it = 0; it < deg; it += 4) {
            float e[4];
            int s[4];
#pragma unroll
            for (int k2 = 0; k2 < 4; ++k2) {
                int pos = r0 + it + k2;
                long long pl = allLds ? sPay[pos]
                                      : (pos < CAP ? sPay[pos] : spill[g0 + pos]);
                bool ok = (it + k2) < deg;
                e[k2] = ok ? __int_as_float((int)(pl >> 32)) : 0.f;
                s[k2] = ok ? (int)(pl & 0xFFFFFFFFll) : 0;
                ssum += e[k2];
            }
            uint4 v[4];
#pragma unroll
            for (int k2 = 0; k2 < 4; ++k2) v[k2] = y4[(size_t)s[k2] * 8 + f];
#pragma unroll
            for (int k2 = 0; k2 < 4; ++k2) {
                acc[0] = fmaf(e[k2], __uint_as_float(v[k2].x << 16), acc[0]);
                acc[1] = fmaf(e[k2], __uint_as_float(v[k2].x & 0xFFFF0000u), acc[1]);
                acc[2] = fmaf(e[k2], __uint_as_float(v[k2].y << 16), acc[2]);
                acc[3] = fmaf(e[k2], __uint_as_float(v[k2].y & 0xFFFF0000u), acc[3]);
                acc[4] = fmaf(e[k2], __uint_as_float(v[k2].z << 16), acc[4]);
                acc[5] = fmaf(e[k2], __uint_as_float(v[k2].z & 0xFFFF0000u), acc[5]);
                acc[6] = fmaf(e[k2], __uint_as_float(v[k2].w << 16), acc[6]);
                acc[7] = fmaf(e[k2], __uint_as_float(v[k2].w & 0xFFFF0000u), acc[7]);
            }
        }
        float rs = 1.0f / (ssum + 1e-16f);
        f32x4 o0 = {acc[0] * rs, acc[1] * rs, acc[2] * rs, acc[3] * rs};
        f32x4 o1 = {acc[4] * rs, acc[5] * rs, acc[6] * rs, acc[7] * rs};
        float* op = &out[(size_t)(d0 + ld) * H + f * 8];
        __builtin_nontemporal_store(o0, (f32x4*)op);
        __builtin_nontemporal_store(o1, (f32x4*)(op + 4));
    }
}

// ---------- Pre-transform: y(bf16) = x @ W^T via MFMA; block 0 zeroes bcnt ----------
__global__ __launch_bounds__(256) void k_xform_mfma(const float* __restrict__ x,
                                                    const float* __restrict__ W,
                                                    ushort* __restrict__ y, int M,
                                                    unsigned* __restrict__ bcnt, int NB) {
    if (bcnt != nullptr && blockIdx.x == 0) {
        for (int j = threadIdx.x; j < NB; j += 256) bcnt[j] = 0u;
    }
    int wid = (blockIdx.x * blockDim.x + threadIdx.x) >> 6;
    int lane = threadIdx.x & 63;
    int n0 = wid * 16;
    if (n0 >= M) return;
    int r = lane & 15, g = lane >> 4;

    short8 bfrag[4][2];
#pragma unroll
    for (int ct = 0; ct < 4; ++ct) {
#pragma unroll
        for (int kh = 0; kh < 2; ++kh) {
            const float* wp = &W[(size_t)(ct * 16 + r) * 64 + kh * 32 + g * 8];
            float4 w0 = *(const float4*)wp;
            float4 w1 = *(const float4*)(wp + 4);
            short8 bf;
            bf[0] = (short)f2bf(w0.x); bf[1] = (short)f2bf(w0.y);
            bf[2] = (short)f2bf(w0.z); bf[3] = (short)f2bf(w0.w);
            bf[4] = (short)f2bf(w1.x); bf[5] = (short)f2bf(w1.y);
            bf[6] = (short)f2bf(w1.z); bf[7] = (short)f2bf(w1.w);
            bfrag[ct][kh] = bf;
        }
    }
    int xr = n0 + r;
    if (xr >= M) xr = M - 1;
    const float* xp = &x[(size_t)xr * 64 + g * 8];
    short8 afrag[2];
#pragma unroll
    for (int kh = 0; kh < 2; ++kh) {
        float4 a0 = *(const float4*)(xp + kh * 32);
        float4 a1 = *(const float4*)(xp + kh * 32 + 4);
        short8 af;
        af[0] = (short)f2bf(a0.x); af[1] = (short)f2bf(a0.y);
        af[2] = (short)f2bf(a0.z); af[3] = (short)f2bf(a0.w);
        af[4] = (short)f2bf(a1.x); af[5] = (short)f2bf(a1.y);
        af[6] = (short)f2bf(a1.z); af[7] = (short)f2bf(a1.w);
        afrag[kh] = af;
    }
#pragma unroll
    for (int ct = 0; ct < 4; ++ct) {
        f32x4 acc = {0.f, 0.f, 0.f, 0.f};
        acc = __builtin_amdgcn_mfma_f32_16x16x32_bf16(afrag[0], bfrag[ct][0], acc, 0, 0, 0);
        acc = __builtin_amdgcn_mfma_f32_16x16x32_bf16(afrag[1], bfrag[ct][1], acc, 0, 0, 0);
#pragma unroll
        for (int q = 0; q < 4; ++q) {
            int row = n0 + g * 4 + q;
            if (row < M) y[(size_t)row * 64 + ct * 16 + r] = f2bf(acc[q]);
        }
    }
}

// ---------- R10 gather kept for fallback path ----------
__global__ __launch_bounds__(256) void k_gather4(const unsigned* __restrict__ base,
                                                 const long long* __restrict__ payload,
                                                 const uint2* __restrict__ y2,
                                                 float* __restrict__ out, int N) {
    int tid = blockIdx.x * blockDim.x + threadIdx.x;
    int lane = threadIdx.x & 63;
    int g = lane >> 4, f = lane & 15;
    int d = (tid >> 6) * 4 + g;
    if (d >= N) return;
    unsigned r0 = base[d], r1 = base[d + 1];
    int deg = (int)(r1 - r0);
    float acc0 = 0.f, acc1 = 0.f, acc2 = 0.f, acc3 = 0.f, ssum = 0.f;
    for (int it = 0; it < deg; it += 4) {
        float e[4];
        int s[4];
#pragma unroll
        for (int k2 = 0; k2 < 4; ++k2) {
            long long pl = __builtin_nontemporal_load(&payload[r0 + it + k2]);
            bool ok = (it + k2) < deg;
            e[k2] = ok ? __int_as_float((int)(pl >> 32)) : 0.f;
            s[k2] = ok ? (int)(pl & 0xFFFFFFFFll) : 0;
            ssum += e[k2];
        }
        uint2 v[4];
#pragma unroll
        for (int k2 = 0; k2 < 4; ++k2) v[k2] = y2[(size_t)s[k2] * 16 + f];
#pragma unroll
        for (int k2 = 0; k2 < 4; ++k2) {
            acc0 = fmaf(e[k2], __uint_as_float(v[k2].x << 16), acc0);
            acc1 = fmaf(e[k2], __uint_as_float(v[k2].x & 0xFFFF0000u), acc1);
            acc2 = fmaf(e[k2], __uint_as_float(v[k2].y << 16), acc2);
            acc3 = fmaf(e[k2], __uint_as_float(v[k2].y & 0xFFFF0000u), acc3);
        }
    }
    float rs = 1.0f / (ssum + 1e-16f);
    f32x4 o = {acc0 * rs, acc1 * rs, acc2 * rs, acc3 * rs};
    __builtin_nontemporal_store(o, (f32x4*)&out[(size_t)d * H + f * 4]);
}

// ================= FALLBACK PATH (R10-proven) =================

__global__ void k_hist(const int* __restrict__ dst, unsigned* __restrict__ cnt, int E) {
    int i = blockIdx.x * blockDim.x + threadIdx.x;
    int st = gridDim.x * blockDim.x;
    int E4 = E >> 2;
    const int4* d4 = (const int4*)dst;
    for (int k = i; k < E4; k += st) {
        int4 v = d4[k];
        atomicAdd(&cnt[v.x], 1u);
        atomicAdd(&cnt[v.y], 1u);
        atomicAdd(&cnt[v.z], 1u);
        atomicAdd(&cnt[v.w], 1u);
    }
    for (int k = (E4 << 2) + i; k < E; k += st) atomicAdd(&cnt[dst[k]], 1u);
}

__global__ __launch_bounds__(1024) void k_scanA(const unsigned* __restrict__ cnt,
                                                unsigned* __restrict__ base,
                                                unsigned* __restrict__ bsum, int N) {
    __shared__ unsigned wsum[16];
    int i = blockIdx.x * 1024 + threadIdx.x;
    unsigned v = (i < N) ? cnt[i] : 0u;
    int lane = threadIdx.x & 63, w = threadIdx.x >> 6;
    unsigned x = v;
#pragma unroll
    for (int off = 1; off < 64; off <<= 1) {
        unsigned y = __shfl_up(x, off, 64);
        if (lane >= off) x += y;
    }
    if (lane == 63) wsum[w] = x;
    __syncthreads();
    if (threadIdx.x < 16) {
        unsigned s = wsum[threadIdx.x];
#pragma unroll
        for (int off = 1; off < 16; off <<= 1) {
            unsigned y = __shfl_up(s, off, 16);
            if ((threadIdx.x & 15) >= off) s += y;
        }
        wsum[threadIdx.x] = s;
    }
    __syncthreads();
    unsigned wbase = (w > 0) ? wsum[w - 1] : 0u;
    if (i < N) base[i] = wbase + x - v;
    if (threadIdx.x == 1023) bsum[blockIdx.x] = wsum[15];
}

__global__ __launch_bounds__(1024) void k_scanB(const unsigned* __restrict__ bsum,
                                                unsigned* __restrict__ boff, int nb) {
    __shared__ unsigned wsum[16];
    int i = threadIdx.x;
    unsigned v = (i < nb) ? bsum[i] : 0u;
    int lane = i & 63, w = i >> 6;
    unsigned x = v;
#pragma unroll
    for (int off = 1; off < 64; off <<= 1) {
        unsigned y = __shfl_up(x, off, 64);
        if (lane >= off) x += y;
    }
    if (lane == 63) wsum[w] = x;
    __syncthreads();
    if (i < 16) {
        unsigned s = wsum[i];
#pragma unroll
        for (int off = 1; off < 16; off <<= 1) {
            unsigned y = __shfl_up(s, off, 16);
            if ((i & 15) >= off) s += y;
        }
        wsum[i] = s;
    }
    __syncthreads();
    unsigned wbase = (w > 0) ? wsum[w - 1] : 0u;
    if (i < nb) boff[i] = wbase + x - v;
}

__global__ void k_scanC(unsigned* __restrict__ base, unsigned* __restrict__ cursor,
                        const unsigned* __restrict__ boff, int N, int E) {
    int i = blockIdx.x * blockDim.x + threadIdx.x;
    int st = gridDim.x * blockDim.x;
    for (; i < N; i += st) {
        unsigned b = base[i] + boff[i >> 10];
        base[i] = b;
        cursor[i] = b;
    }
    if (blockIdx.x == 0 && threadIdx.x == 0) base[N] = (unsigned)E;
}

__global__ void k_permute_part(const int* __restrict__ dst, const int* __restrict__ src,
                               const float* __restrict__ t, unsigned* __restrict__ cursor,
                               int2* __restrict__ payload, int E, int N) {
    const float inv = 1.0f / (0.5f + 1e-8f);
    int part = blockIdx.x & (NXCD - 1);
    int nslice = gridDim.x >> 3;
    int sblk = blockIdx.x >> 3;
    int lo = (int)((long long)part * N / NXCD);
    int hi = (int)((long long)(part + 1) * N / NXCD);
    int e0 = (int)((long long)sblk * E / nslice);
    int e1 = (int)((long long)(sblk + 1) * E / nslice);
    for (int i = e0 + threadIdx.x; i < e1; i += blockDim.x) {
        int d = dst[i];
        if (d >= lo && d < hi) {
            unsigned pos = atomicAdd(&cursor[d], 1u);
            float e = __expf(t[i] * inv);
            payload[pos] = make_int2(src[i], __float_as_int(e));
        }
    }
}

__global__ void k_permute_pack(const int* __restrict__ dst, const int* __restrict__ src,
                               const float* __restrict__ t, unsigned* __restrict__ cursor,
                               int2* __restrict__ payload, int E) {
    const float inv = 1.0f / (0.5f + 1e-8f);
    int i = blockIdx.x * blockDim.x + threadIdx.x;
    int st = gridDim.x * blockDim.x;
    for (; i < E; i += st) {
        unsigned pos = atomicAdd(&cursor[dst[i]], 1u);
        float e = __expf(t[i] * inv);
        payload[pos] = make_int2(src[i], __float_as_int(e));
    }
}

__global__ __launch_bounds__(256) void k_gather_fb(const unsigned* __restrict__ base,
                                                   const int2* __restrict__ payload,
                                                   const float* __restrict__ x_src,
                                                   const float* __restrict__ W,
                                                   float* __restrict__ out, int N) {
    __shared__ float wt[H * H];
    for (int idx = threadIdx.x; idx < H * H; idx += blockDim.x) {
        int j = idx >> 6, k = idx & 63;
        wt[k * H + j] = W[idx];
    }
    __syncthreads();
    int lane = threadIdx.x & 63;
    int wid = (blockIdx.x * blockDim.x + threadIdx.x) >> 6;
    int nw = (gridDim.x * blockDim.x) >> 6;
    for (int d = wid; d < N; d += nw) {
        unsigned r0 = base[d], r1 = base[d + 1];
        int deg = (int)(r1 - r0);
        float acc = 0.0f, ssum = 0.0f;
        for (int c = 0; c < deg; c += 64) {
            int j = c + lane;
            int cd = min(64, deg - c);
            float e = 0.0f;
            int sidx = 0;
            if (j < deg) {
                int2 p = payload[r0 + j];
                sidx = p.x;
                e = __int_as_float(p.y);
            }
            float cs = e;
#pragma unroll
            for (int off = 32; off >= 1; off >>= 1) cs += __shfl_xor(cs, off, 64);
            ssum += cs;
            for (int q = 0; q < cd; q += 8) {
                float a[8];
                int sv[8];
                float v[8];
#pragma unroll
                for (int u = 0; u < 8; ++u) {
                    a[u] = __shfl(e, q + u, 64);
                    sv[u] = __shfl(sidx, q + u, 64);
                }
#pragma unroll
                for (int u = 0; u < 8; ++u) v[u] = x_src[(size_t)sv[u] * H + lane];
#pragma unroll
                for (int u = 0; u < 8; ++u) acc = fmaf(a[u], v[u], acc);
            }
        }
        acc *= 1.0f / (ssum + 1e-16f);
        float o = 0.0f;
#pragma unroll
        for (int k = 0; k < H; ++k) o = fmaf(__shfl(acc, k, 64), wt[k * H + lane], o);
        out[(size_t)d * H + lane] = o;
    }
}

extern "C" void kernel_launch(void* const* d_in, const int* in_sizes, int n_in,
                              void* d_out, int out_size, void* d_ws, size_t ws_size,
                              hipStream_t stream) {
    const float* x_src = (const float*)d_in[0];
    const float* W = (const float*)d_in[2];
    const int* edge_index = (const int*)d_in[3];
    const float* t = (const float*)d_in[4];

    int E = in_sizes[4];
    int N = in_sizes[1] / H;  // N_DST
    int M = in_sizes[0] / H;  // N_SRC
    const int* src = edge_index;
    const int* dst = edge_index + E;

    unsigned* base = (unsigned*)d_ws;
    unsigned* cursor = base + (size_t)N + 1;
    unsigned* bsum = cursor + N;
    unsigned* boff = bsum + 1024;
    unsigned* bmeta = boff + 1024;
    unsigned* bcnt = bmeta + 32;
    unsigned* bstart2 = bcnt + 1024;
    unsigned* bcur2 = bstart2 + 1056;
    size_t head_u32 = (size_t)(2 * N + 1) + 1024 + 1024 + 32 + 1024 + 1056 + 1056;
    size_t pay_off = (head_u32 * 4 + 15) & ~(size_t)15;
    int2* payload = (int2*)((char*)d_ws + pay_off);
    unsigned long long* bin1 = (unsigned long long*)payload;  // alias
    size_t b2_off = (pay_off + (size_t)E * 8 + 15) & ~(size_t)15;
    unsigned long long* bin2 = (unsigned long long*)((char*)d_ws + b2_off);
    size_t y_off = b2_off + (size_t)E * 8;
    ushort* y = (ushort*)((char*)d_ws + y_off);

    bool have_y_small = (ws_size >= pay_off + (size_t)E * 8 + (size_t)M * H * 2 + 32);
    bool have_full = (ws_size >= y_off + (size_t)M * H * 2);
    bool packable = (M < (1 << 17)) && (N < (1 << 17));

    int nb = (N + 1023) / 1024;
    int ps0 = (N + NXCD - 1) / NXCD;
    int partsize = (ps0 + 255) & ~255;
    int NB = (N + 255) >> 8;

    int blocks_e = (E + 255) / 256;
    if (blocks_e > 2048) blocks_e = 2048;

    if (have_full && packable && NB <= 1024) {
        int xblocks = ((M + 15) / 16 * 64 + 255) / 256;
        k_xform_mfma<<<xblocks, 256, 0, stream>>>(x_src, W, y, M, bcnt, NB);
        k_count<<<1024, 256, 0, stream>>>(dst, bcnt, E, NB);
        k_scan_small<<<1, 1024, 0, stream>>>(bcnt, bstart2, bcur2, bmeta, NB, partsize, E);
        int nbin = (E + CH - 1) / CH;
        k_bin<<<nbin, 256, 0, stream>>>(dst, src, t, bmeta + 16, bin1, E, partsize);
        int nb2 = (E / NXCD + CH2 - 1) / CH2 + 1;
        dim3 g2(nb2, NXCD);
        k_bin2<<<g2, 256, 0, stream>>>(bmeta, bin1, bcur2, bin2, partsize);
        k_fuse<<<NB, 1024, 0, stream>>>(bstart2, bin2, (long long*)payload,
                                        (const uint4*)y, (float*)d_out, N);
    } else if (have_y_small) {
        ushort* y2p = (ushort*)((char*)d_ws + pay_off + (size_t)E * 8);
        hipMemsetAsync(cursor, 0, (size_t)N * sizeof(unsigned), stream);
        k_hist<<<1024, 256, 0, stream>>>(dst, cursor, E);
        k_scanA<<<nb, 1024, 0, stream>>>(cursor, base, bsum, N);
        k_scanB<<<1, 1024, 0, stream>>>(bsum, boff, nb);
        k_scanC<<<512, 256, 0, stream>>>(base, cursor, boff, N, E);
        int xblocks = ((M + 15) / 16 * 64 + 255) / 256;
        k_xform_mfma<<<xblocks, 256, 0, stream>>>(x_src, W, y2p, M, nullptr, 0);
        k_permute_part<<<2048, 256, 0, stream>>>(dst, src, t, cursor, payload, E, N);
        int gblocks = (N + 15) / 16;
        k_gather4<<<gblocks, 256, 0, stream>>>(base, (const long long*)payload,
                                               (const uint2*)y2p, (float*)d_out, N);
    } else {
        hipMemsetAsync(cursor, 0, (size_t)N * sizeof(unsigned), stream);
        k_hist<<<1024, 256, 0, stream>>>(dst, cursor, E);
        k_scanA<<<nb, 1024, 0, stream>>>(cursor, base, bsum, N);
        k_scanB<<<1, 1024, 0, stream>>>(bsum, boff, nb);
        k_scanC<<<512, 256, 0, stream>>>(base, cursor, boff, N, E);
        k_permute_pack<<<blocks_e, 256, 0, stream>>>(dst, src, t, cursor, payload, E);
        k_gather_fb<<<4096, 256, 0, stream>>>(base, payload, x_src, W, (float*)d_out, N);
    }
}

// Round 19
// 102.647 us; speedup vs baseline: 1.3319x; 1.2054x over previous
//
#include <hip/hip_runtime.h>
#include <math.h>

#define H 64
#define NXCD 8
#define CH3 8192
#define CAP 4096

typedef __attribute__((ext_vector_type(8))) short short8;
typedef __attribute__((ext_vector_type(4))) float f32x4;

__device__ inline ushort f2bf(float f) {
    union { float f; unsigned u; } v;
    v.f = f;
    unsigned r = v.u + 0x7FFFu + ((v.u >> 16) & 1u);
    return (ushort)(r >> 16);
}

// ================= FAST PATH =================

// ---------- Stage 0: bucket-level histogram via LDS ----------
__global__ __launch_bounds__(256) void k_count(const int* __restrict__ dst,
                                               unsigned* __restrict__ bcnt, int E, int NB) {
    __shared__ unsigned lc[1024];
    for (int j = threadIdx.x; j < NB; j += 256) lc[j] = 0;
    __syncthreads();
    int i = blockIdx.x * blockDim.x + threadIdx.x;
    int st = gridDim.x * blockDim.x;
    int E4 = E >> 2;
    const int4* d4 = (const int4*)dst;
    for (int k = i; k < E4; k += st) {
        int4 v = d4[k];
        atomicAdd(&lc[v.x >> 8], 1u);
        atomicAdd(&lc[v.y >> 8], 1u);
        atomicAdd(&lc[v.z >> 8], 1u);
        atomicAdd(&lc[v.w >> 8], 1u);
    }
    for (int k = (E4 << 2) + i; k < E; k += st) atomicAdd(&lc[dst[k] >> 8], 1u);
    __syncthreads();
    for (int j = threadIdx.x; j < NB; j += 256)
        if (lc[j]) atomicAdd(&bcnt[j], lc[j]);
}

// ---------- Stage 1: single-block scan of bucket counts ----------
__global__ __launch_bounds__(1024) void k_scan_small(const unsigned* __restrict__ bcnt,
                                                     unsigned* __restrict__ bstart2,
                                                     unsigned* __restrict__ bcur2,
                                                     int NB, int E) {
    __shared__ unsigned wsum[16];
    __shared__ unsigned sex[1025];
    int i = threadIdx.x;
    unsigned v = (i < NB) ? bcnt[i] : 0u;
    int lane = i & 63, w = i >> 6;
    unsigned x = v;
#pragma unroll
    for (int off = 1; off < 64; off <<= 1) {
        unsigned y = __shfl_up(x, off, 64);
        if (lane >= off) x += y;
    }
    if (lane == 63) wsum[w] = x;
    __syncthreads();
    if (i < 16) {
        unsigned s = wsum[i];
#pragma unroll
        for (int off = 1; off < 16; off <<= 1) {
            unsigned y = __shfl_up(s, off, 16);
            if ((i & 15) >= off) s += y;
        }
        wsum[i] = s;
    }
    __syncthreads();
    unsigned wbase = (w > 0) ? wsum[w - 1] : 0u;
    unsigned excl = wbase + x - v;
    sex[i] = excl;
    if (i == 0) sex[1024] = (unsigned)E;
    __syncthreads();
    if (i <= NB) bstart2[i] = sex[i];
    if (i < NB) bcur2[i] = sex[i];
}

// ---------- Stage 2 (single pass): chunk -> LDS bucket-sort -> contiguous runs ----------
// Each block: count its chunk's 391 buckets in LDS, scan, reserve global space
// (<=NB atomics), scatter packed entries into LDS slab SORTED by bucket, then
// write each bucket's run contiguously. Replaces the two-pass bin/bin2.
__global__ __launch_bounds__(1024) void k_bin_direct(const int* __restrict__ dst,
                                                     const int* __restrict__ src,
                                                     const float* __restrict__ t,
                                                     unsigned* __restrict__ bcur2,
                                                     unsigned long long* __restrict__ bin2,
                                                     int E) {
    __shared__ unsigned long long slab[CH3];
    __shared__ unsigned lcnt[1024];
    __shared__ unsigned lofs[1024];
    __shared__ unsigned gofs[1024];
    __shared__ unsigned wsum[16];
    int tid = threadIdx.x;
    int e0 = blockIdx.x * CH3;
    int e1 = min(e0 + CH3, E);
    int cnt = e1 - e0;
    lcnt[tid] = 0;
    __syncthreads();
    // count buckets in this chunk
    for (int i = e0 + tid; i < e1; i += 1024) atomicAdd(&lcnt[dst[i] >> 8], 1u);
    __syncthreads();
    // exclusive scan of 1024 counters (verified k_scan_small pattern)
    unsigned v = lcnt[tid];
    int lane = tid & 63, w = tid >> 6;
    unsigned x = v;
#pragma unroll
    for (int off = 1; off < 64; off <<= 1) {
        unsigned y = __shfl_up(x, off, 64);
        if (lane >= off) x += y;
    }
    if (lane == 63) wsum[w] = x;
    __syncthreads();
    if (tid < 16) {
        unsigned s = wsum[tid];
#pragma unroll
        for (int off = 1; off < 16; off <<= 1) {
            unsigned y = __shfl_up(s, off, 16);
            if ((tid & 15) >= off) s += y;
        }
        wsum[tid] = s;
    }
    __syncthreads();
    unsigned excl = ((w > 0) ? wsum[w - 1] : 0u) + x - v;
    lofs[tid] = excl;
    gofs[tid] = v ? atomicAdd(&bcur2[tid], v) : 0u;
    __syncthreads();
    lcnt[tid] = excl;  // running cursor
    __syncthreads();
    // scatter into LDS slab sorted by bucket
    const float inv = 1.0f / (0.5f + 1e-8f);
    for (int i = e0 + tid; i < e1; i += 1024) {
        int d = dst[i];
        unsigned eb = f2bf(__expf(t[i] * inv));
        unsigned long long u = ((unsigned long long)d << 33)
                             | ((unsigned long long)src[i] << 16)
                             | (unsigned long long)eb;
        unsigned pos = atomicAdd(&lcnt[d >> 8], 1u);
        slab[pos] = u;
    }
    __syncthreads();
    // write out: slab[j]'s bucket is recoverable from its d field
    for (int j = tid; j < cnt; j += 1024) {
        unsigned long long u = slab[j];
        int b = (int)(u >> 41);  // (d >> 8) where d = u >> 33
        bin2[gofs[b] + (j - lofs[b])] = u;
    }
}

// ---------- Stage 3 (FUSED): bucket bin -> LDS CSR slab -> direct gather (verified R18) ----------
__global__ __launch_bounds__(1024) void k_fuse(const unsigned* __restrict__ bstart2,
                                               const unsigned long long* __restrict__ bin2,
                                               long long* __restrict__ spill,
                                               const uint4* __restrict__ y4,
                                               float* __restrict__ out, int N) {
    __shared__ long long sPay[CAP + 4];
    __shared__ unsigned lcnt[256];
    __shared__ unsigned lrel[257];
    __shared__ unsigned wsum[4];
    int b = blockIdx.x;
    int d0 = b << 8;
    int d1 = min(d0 + 256, N);
    int nd = d1 - d0;
    unsigned g0 = bstart2[b];
    unsigned g1 = bstart2[b + 1];
    int cnt = (int)(g1 - g0);
    int tid = threadIdx.x;
    if (tid < 256) lcnt[tid] = 0;
    __syncthreads();
    for (int i = (int)g0 + tid; i < (int)g1; i += 1024)
        atomicAdd(&lcnt[(int)(bin2[i] >> 33) - d0], 1u);
    __syncthreads();
    if (tid < 256) {
        unsigned v = lcnt[tid];
        int lane = tid & 63, w = tid >> 6;
        unsigned x = v;
#pragma unroll
        for (int off = 1; off < 64; off <<= 1) {
            unsigned y = __shfl_up(x, off, 64);
            if (lane >= off) x += y;
        }
        if (lane == 63) wsum[w] = x;
        __syncthreads();
        if (tid == 0) {
            unsigned s = 0;
#pragma unroll
            for (int k = 0; k < 4; ++k) { unsigned tq = wsum[k]; wsum[k] = s; s += tq; }
        }
        __syncthreads();
        unsigned excl = wsum[w] + x - v;
        lrel[tid] = excl;
        lcnt[tid] = excl;
        if (tid == 0) lrel[256] = (unsigned)cnt;
    } else {
        __syncthreads();
        __syncthreads();
    }
    __syncthreads();
    for (int i = (int)g0 + tid; i < (int)g1; i += 1024) {
        unsigned long long u = bin2[i];
        int d = (int)(u >> 33);
        int s = (int)((u >> 16) & 0x1FFFF);
        unsigned ef = (unsigned)(u & 0xFFFFu) << 16;
        unsigned lpos = atomicAdd(&lcnt[d - d0], 1u);
        long long pv = ((long long)(int)ef << 32) | (unsigned)s;
        if (lpos < CAP) sPay[lpos] = pv;
        else spill[g0 + lpos] = pv;  // statistically never; correctness only
    }
    __syncthreads();
    int g = tid >> 3, f = tid & 7;
#pragma unroll
    for (int round = 0; round < 2; ++round) {
        int ld = round * 128 + g;
        if (ld >= nd) continue;
        int r0 = (int)lrel[ld];
        int r1 = (int)lrel[ld + 1];
        int deg = r1 - r0;
        float acc[8] = {0.f, 0.f, 0.f, 0.f, 0.f, 0.f, 0.f, 0.f};
        float ssum = 0.f;
        bool allLds = (r1 + 3 <= CAP);
        for (int it = 0; it < deg; it += 4) {
            float e[4];
            int s[4];
#pragma unroll
            for (int k2 = 0; k2 < 4; ++k2) {
                int pos = r0 + it + k2;
                long long pl = allLds ? sPay[pos]
                                      : (pos < CAP ? sPay[pos] : spill[g0 + pos]);
                bool ok = (it + k2) < deg;
                e[k2] = ok ? __int_as_float((int)(pl >> 32)) : 0.f;
                s[k2] = ok ? (int)(pl & 0xFFFFFFFFll) : 0;
                ssum += e[k2];
            }
            uint4 v[4];
#pragma unroll
            for (int k2 = 0; k2 < 4; ++k2) v[k2] = y4[(size_t)s[k2] * 8 + f];
#pragma unroll
            for (int k2 = 0; k2 < 4; ++k2) {
                acc[0] = fmaf(e[k2], __uint_as_float(v[k2].x << 16), acc[0]);
                acc[1] = fmaf(e[k2], __uint_as_float(v[k2].x & 0xFFFF0000u), acc[1]);
                acc[2] = fmaf(e[k2], __uint_as_float(v[k2].y << 16), acc[2]);
                acc[3] = fmaf(e[k2], __uint_as_float(v[k2].y & 0xFFFF0000u), acc[3]);
                acc[4] = fmaf(e[k2], __uint_as_float(v[k2].z << 16), acc[4]);
                acc[5] = fmaf(e[k2], __uint_as_float(v[k2].z & 0xFFFF0000u), acc[5]);
                acc[6] = fmaf(e[k2], __uint_as_float(v[k2].w << 16), acc[6]);
                acc[7] = fmaf(e[k2], __uint_as_float(v[k2].w & 0xFFFF0000u), acc[7]);
            }
        }
        float rs = 1.0f / (ssum + 1e-16f);
        f32x4 o0 = {acc[0] * rs, acc[1] * rs, acc[2] * rs, acc[3] * rs};
        f32x4 o1 = {acc[4] * rs, acc[5] * rs, acc[6] * rs, acc[7] * rs};
        float* op = &out[(size_t)(d0 + ld) * H + f * 8];
        __builtin_nontemporal_store(o0, (f32x4*)op);
        __builtin_nontemporal_store(o1, (f32x4*)(op + 4));
    }
}

// ---------- Pre-transform: y(bf16) = x @ W^T via MFMA; block 0 zeroes bcnt ----------
__global__ __launch_bounds__(256) void k_xform_mfma(const float* __restrict__ x,
                                                    const float* __restrict__ W,
                                                    ushort* __restrict__ y, int M,
                                                    unsigned* __restrict__ bcnt, int NB) {
    if (bcnt != nullptr && blockIdx.x == 0) {
        for (int j = threadIdx.x; j < NB; j += 256) bcnt[j] = 0u;
    }
    int wid = (blockIdx.x * blockDim.x + threadIdx.x) >> 6;
    int lane = threadIdx.x & 63;
    int n0 = wid * 16;
    if (n0 >= M) return;
    int r = lane & 15, g = lane >> 4;

    short8 bfrag[4][2];
#pragma unroll
    for (int ct = 0; ct < 4; ++ct) {
#pragma unroll
        for (int kh = 0; kh < 2; ++kh) {
            const float* wp = &W[(size_t)(ct * 16 + r) * 64 + kh * 32 + g * 8];
            float4 w0 = *(const float4*)wp;
            float4 w1 = *(const float4*)(wp + 4);
            short8 bf;
            bf[0] = (short)f2bf(w0.x); bf[1] = (short)f2bf(w0.y);
            bf[2] = (short)f2bf(w0.z); bf[3] = (short)f2bf(w0.w);
            bf[4] = (short)f2bf(w1.x); bf[5] = (short)f2bf(w1.y);
            bf[6] = (short)f2bf(w1.z); bf[7] = (short)f2bf(w1.w);
            bfrag[ct][kh] = bf;
        }
    }
    int xr = n0 + r;
    if (xr >= M) xr = M - 1;
    const float* xp = &x[(size_t)xr * 64 + g * 8];
    short8 afrag[2];
#pragma unroll
    for (int kh = 0; kh < 2; ++kh) {
        float4 a0 = *(const float4*)(xp + kh * 32);
        float4 a1 = *(const float4*)(xp + kh * 32 + 4);
        short8 af;
        af[0] = (short)f2bf(a0.x); af[1] = (short)f2bf(a0.y);
        af[2] = (short)f2bf(a0.z); af[3] = (short)f2bf(a0.w);
        af[4] = (short)f2bf(a1.x); af[5] = (short)f2bf(a1.y);
        af[6] = (short)f2bf(a1.z); af[7] = (short)f2bf(a1.w);
        afrag[kh] = af;
    }
#pragma unroll
    for (int ct = 0; ct < 4; ++ct) {
        f32x4 acc = {0.f, 0.f, 0.f, 0.f};
        acc = __builtin_amdgcn_mfma_f32_16x16x32_bf16(afrag[0], bfrag[ct][0], acc, 0, 0, 0);
        acc = __builtin_amdgcn_mfma_f32_16x16x32_bf16(afrag[1], bfrag[ct][1], acc, 0, 0, 0);
#pragma unroll
        for (int q = 0; q < 4; ++q) {
            int row = n0 + g * 4 + q;
            if (row < M) y[(size_t)row * 64 + ct * 16 + r] = f2bf(acc[q]);
        }
    }
}

// ---------- R10 gather kept for fallback path ----------
__global__ __launch_bounds__(256) void k_gather4(const unsigned* __restrict__ base,
                                                 const long long* __restrict__ payload,
                                                 const uint2* __restrict__ y2,
                                                 float* __restrict__ out, int N) {
    int tid = blockIdx.x * blockDim.x + threadIdx.x;
    int lane = threadIdx.x & 63;
    int g = lane >> 4, f = lane & 15;
    int d = (tid >> 6) * 4 + g;
    if (d >= N) return;
    unsigned r0 = base[d], r1 = base[d + 1];
    int deg = (int)(r1 - r0);
    float acc0 = 0.f, acc1 = 0.f, acc2 = 0.f, acc3 = 0.f, ssum = 0.f;
    for (int it = 0; it < deg; it += 4) {
        float e[4];
        int s[4];
#pragma unroll
        for (int k2 = 0; k2 < 4; ++k2) {
            long long pl = __builtin_nontemporal_load(&payload[r0 + it + k2]);
            bool ok = (it + k2) < deg;
            e[k2] = ok ? __int_as_float((int)(pl >> 32)) : 0.f;
            s[k2] = ok ? (int)(pl & 0xFFFFFFFFll) : 0;
            ssum += e[k2];
        }
        uint2 v[4];
#pragma unroll
        for (int k2 = 0; k2 < 4; ++k2) v[k2] = y2[(size_t)s[k2] * 16 + f];
#pragma unroll
        for (int k2 = 0; k2 < 4; ++k2) {
            acc0 = fmaf(e[k2], __uint_as_float(v[k2].x << 16), acc0);
            acc1 = fmaf(e[k2], __uint_as_float(v[k2].x & 0xFFFF0000u), acc1);
            acc2 = fmaf(e[k2], __uint_as_float(v[k2].y << 16), acc2);
            acc3 = fmaf(e[k2], __uint_as_float(v[k2].y & 0xFFFF0000u), acc3);
        }
    }
    float rs = 1.0f / (ssum + 1e-16f);
    f32x4 o = {acc0 * rs, acc1 * rs, acc2 * rs, acc3 * rs};
    __builtin_nontemporal_store(o, (f32x4*)&out[(size_t)d * H + f * 4]);
}

// ================= FALLBACK PATH (R10-proven) =================

__global__ void k_hist(const int* __restrict__ dst, unsigned* __restrict__ cnt, int E) {
    int i = blockIdx.x * blockDim.x + threadIdx.x;
    int st = gridDim.x * blockDim.x;
    int E4 = E >> 2;
    const int4* d4 = (const int4*)dst;
    for (int k = i; k < E4; k += st) {
        int4 v = d4[k];
        atomicAdd(&cnt[v.x], 1u);
        atomicAdd(&cnt[v.y], 1u);
        atomicAdd(&cnt[v.z], 1u);
        atomicAdd(&cnt[v.w], 1u);
    }
    for (int k = (E4 << 2) + i; k < E; k += st) atomicAdd(&cnt[dst[k]], 1u);
}

__global__ __launch_bounds__(1024) void k_scanA(const unsigned* __restrict__ cnt,
                                                unsigned* __restrict__ base,
                                                unsigned* __restrict__ bsum, int N) {
    __shared__ unsigned wsum[16];
    int i = blockIdx.x * 1024 + threadIdx.x;
    unsigned v = (i < N) ? cnt[i] : 0u;
    int lane = threadIdx.x & 63, w = threadIdx.x >> 6;
    unsigned x = v;
#pragma unroll
    for (int off = 1; off < 64; off <<= 1) {
        unsigned y = __shfl_up(x, off, 64);
        if (lane >= off) x += y;
    }
    if (lane == 63) wsum[w] = x;
    __syncthreads();
    if (threadIdx.x < 16) {
        unsigned s = wsum[threadIdx.x];
#pragma unroll
        for (int off = 1; off < 16; off <<= 1) {
            unsigned y = __shfl_up(s, off, 16);
            if ((threadIdx.x & 15) >= off) s += y;
        }
        wsum[threadIdx.x] = s;
    }
    __syncthreads();
    unsigned wbase = (w > 0) ? wsum[w - 1] : 0u;
    if (i < N) base[i] = wbase + x - v;
    if (threadIdx.x == 1023) bsum[blockIdx.x] = wsum[15];
}

__global__ __launch_bounds__(1024) void k_scanB(const unsigned* __restrict__ bsum,
                                                unsigned* __restrict__ boff, int nb) {
    __shared__ unsigned wsum[16];
    int i = threadIdx.x;
    unsigned v = (i < nb) ? bsum[i] : 0u;
    int lane = i & 63, w = i >> 6;
    unsigned x = v;
#pragma unroll
    for (int off = 1; off < 64; off <<= 1) {
        unsigned y = __shfl_up(x, off, 64);
        if (lane >= off) x += y;
    }
    if (lane == 63) wsum[w] = x;
    __syncthreads();
    if (i < 16) {
        unsigned s = wsum[i];
#pragma unroll
        for (int off = 1; off < 16; off <<= 1) {
            unsigned y = __shfl_up(s, off, 16);
            if ((i & 15) >= off) s += y;
        }
        wsum[i] = s;
    }
    __syncthreads();
    unsigned wbase = (w > 0) ? wsum[w - 1] : 0u;
    if (i < nb) boff[i] = wbase + x - v;
}

__global__ void k_scanC(unsigned* __restrict__ base, unsigned* __restrict__ cursor,
                        const unsigned* __restrict__ boff, int N, int E) {
    int i = blockIdx.x * blockDim.x + threadIdx.x;
    int st = gridDim.x * blockDim.x;
    for (; i < N; i += st) {
        unsigned b = base[i] + boff[i >> 10];
        base[i] = b;
        cursor[i] = b;
    }
    if (blockIdx.x == 0 && threadIdx.x == 0) base[N] = (unsigned)E;
}

__global__ void k_permute_part(const int* __restrict__ dst, const int* __restrict__ src,
                               const float* __restrict__ t, unsigned* __restrict__ cursor,
                               int2* __restrict__ payload, int E, int N) {
    const float inv = 1.0f / (0.5f + 1e-8f);
    int part = blockIdx.x & (NXCD - 1);
    int nslice = gridDim.x >> 3;
    int sblk = blockIdx.x >> 3;
    int lo = (int)((long long)part * N / NXCD);
    int hi = (int)((long long)(part + 1) * N / NXCD);
    int e0 = (int)((long long)sblk * E / nslice);
    int e1 = (int)((long long)(sblk + 1) * E / nslice);
    for (int i = e0 + threadIdx.x; i < e1; i += blockDim.x) {
        int d = dst[i];
        if (d >= lo && d < hi) {
            unsigned pos = atomicAdd(&cursor[d], 1u);
            float e = __expf(t[i] * inv);
            payload[pos] = make_int2(src[i], __float_as_int(e));
        }
    }
}

__global__ void k_permute_pack(const int* __restrict__ dst, const int* __restrict__ src,
                               const float* __restrict__ t, unsigned* __restrict__ cursor,
                               int2* __restrict__ payload, int E) {
    const float inv = 1.0f / (0.5f + 1e-8f);
    int i = blockIdx.x * blockDim.x + threadIdx.x;
    int st = gridDim.x * blockDim.x;
    for (; i < E; i += st) {
        unsigned pos = atomicAdd(&cursor[dst[i]], 1u);
        float e = __expf(t[i] * inv);
        payload[pos] = make_int2(src[i], __float_as_int(e));
    }
}

__global__ __launch_bounds__(256) void k_gather_fb(const unsigned* __restrict__ base,
                                                   const int2* __restrict__ payload,
                                                   const float* __restrict__ x_src,
                                                   const float* __restrict__ W,
                                                   float* __restrict__ out, int N) {
    __shared__ float wt[H * H];
    for (int idx = threadIdx.x; idx < H * H; idx += blockDim.x) {
        int j = idx >> 6, k = idx & 63;
        wt[k * H + j] = W[idx];
    }
    __syncthreads();
    int lane = threadIdx.x & 63;
    int wid = (blockIdx.x * blockDim.x + threadIdx.x) >> 6;
    int nw = (gridDim.x * blockDim.x) >> 6;
    for (int d = wid; d < N; d += nw) {
        unsigned r0 = base[d], r1 = base[d + 1];
        int deg = (int)(r1 - r0);
        float acc = 0.0f, ssum = 0.0f;
        for (int c = 0; c < deg; c += 64) {
            int j = c + lane;
            int cd = min(64, deg - c);
            float e = 0.0f;
            int sidx = 0;
            if (j < deg) {
                int2 p = payload[r0 + j];
                sidx = p.x;
                e = __int_as_float(p.y);
            }
            float cs = e;
#pragma unroll
            for (int off = 32; off >= 1; off >>= 1) cs += __shfl_xor(cs, off, 64);
            ssum += cs;
            for (int q = 0; q < cd; q += 8) {
                float a[8];
                int sv[8];
                float v[8];
#pragma unroll
                for (int u = 0; u < 8; ++u) {
                    a[u] = __shfl(e, q + u, 64);
                    sv[u] = __shfl(sidx, q + u, 64);
                }
#pragma unroll
                for (int u = 0; u < 8; ++u) v[u] = x_src[(size_t)sv[u] * H + lane];
#pragma unroll
                for (int u = 0; u < 8; ++u) acc = fmaf(a[u], v[u], acc);
            }
        }
        acc *= 1.0f / (ssum + 1e-16f);
        float o = 0.0f;
#pragma unroll
        for (int k = 0; k < H; ++k) o = fmaf(__shfl(acc, k, 64), wt[k * H + lane], o);
        out[(size_t)d * H + lane] = o;
    }
}

extern "C" void kernel_launch(void* const* d_in, const int* in_sizes, int n_in,
                              void* d_out, int out_size, void* d_ws, size_t ws_size,
                              hipStream_t stream) {
    const float* x_src = (const float*)d_in[0];
    const float* W = (const float*)d_in[2];
    const int* edge_index = (const int*)d_in[3];
    const float* t = (const float*)d_in[4];

    int E = in_sizes[4];
    int N = in_sizes[1] / H;  // N_DST
    int M = in_sizes[0] / H;  // N_SRC
    const int* src = edge_index;
    const int* dst = edge_index + E;

    unsigned* base = (unsigned*)d_ws;
    unsigned* cursor = base + (size_t)N + 1;
    unsigned* bsum = cursor + N;
    unsigned* boff = bsum + 1024;
    unsigned* bmeta = boff + 1024;
    unsigned* bcnt = bmeta + 32;
    unsigned* bstart2 = bcnt + 1024;
    unsigned* bcur2 = bstart2 + 1056;
    size_t head_u32 = (size_t)(2 * N + 1) + 1024 + 1024 + 32 + 1024 + 1056 + 1056;
    size_t pay_off = (head_u32 * 4 + 15) & ~(size_t)15;
    int2* payload = (int2*)((char*)d_ws + pay_off);  // fast path: spill region only
    size_t b2_off = (pay_off + (size_t)E * 8 + 15) & ~(size_t)15;
    unsigned long long* bin2 = (unsigned long long*)((char*)d_ws + b2_off);
    size_t y_off = b2_off + (size_t)E * 8;
    ushort* y = (ushort*)((char*)d_ws + y_off);

    bool have_y_small = (ws_size >= pay_off + (size_t)E * 8 + (size_t)M * H * 2 + 32);
    bool have_full = (ws_size >= y_off + (size_t)M * H * 2);
    bool packable = (M < (1 << 17)) && (N < (1 << 17));

    int nb = (N + 1023) / 1024;
    int NB = (N + 255) >> 8;

    int blocks_e = (E + 255) / 256;
    if (blocks_e > 2048) blocks_e = 2048;

    if (have_full && packable && NB <= 1024) {
        int xblocks = ((M + 15) / 16 * 64 + 255) / 256;
        k_xform_mfma<<<xblocks, 256, 0, stream>>>(x_src, W, y, M, bcnt, NB);
        k_count<<<1024, 256, 0, stream>>>(dst, bcnt, E, NB);
        k_scan_small<<<1, 1024, 0, stream>>>(bcnt, bstart2, bcur2, NB, E);
        int nchunks = (E + CH3 - 1) / CH3;
        k_bin_direct<<<nchunks, 1024, 0, stream>>>(dst, src, t, bcur2, bin2, E);
        k_fuse<<<NB, 1024, 0, stream>>>(bstart2, bin2, (long long*)payload,
                                        (const uint4*)y, (float*)d_out, N);
    } else if (have_y_small) {
        ushort* y2p = (ushort*)((char*)d_ws + pay_off + (size_t)E * 8);
        hipMemsetAsync(cursor, 0, (size_t)N * sizeof(unsigned), stream);
        k_hist<<<1024, 256, 0, stream>>>(dst, cursor, E);
        k_scanA<<<nb, 1024, 0, stream>>>(cursor, base, bsum, N);
        k_scanB<<<1, 1024, 0, stream>>>(bsum, boff, nb);
        k_scanC<<<512, 256, 0, stream>>>(base, cursor, boff, N, E);
        int xblocks = ((M + 15) / 16 * 64 + 255) / 256;
        k_xform_mfma<<<xblocks, 256, 0, stream>>>(x_src, W, y2p, M, nullptr, 0);
        k_permute_part<<<2048, 256, 0, stream>>>(dst, src, t, cursor, payload, E, N);
        int gblocks = (N + 15) / 16;
        k_gather4<<<gblocks, 256, 0, stream>>>(base, (const long long*)payload,
                                               (const uint2*)y2p, (float*)d_out, N);
    } else {
        hipMemsetAsync(cursor, 0, (size_t)N * sizeof(unsigned), stream);
        k_hist<<<1024, 256, 0, stream>>>(dst, cursor, E);
        k_scanA<<<nb, 1024, 0, stream>>>(cursor, base, bsum, N);
        k_scanB<<<1, 1024, 0, stream>>>(bsum, boff, nb);
        k_scanC<<<512, 256, 0, stream>>>(base, cursor, boff, N, E);
        k_permute_pack<<<blocks_e, 256, 0, stream>>>(dst, src, t, cursor, payload, E);
        k_gather_fb<<<4096, 256, 0, stream>>>(base, payload, x_src, W, (float*)d_out, N);
    }
}

// Round 20
// 73.440 us; speedup vs baseline: 1.8616x; 1.3977x over previous
//
#include <hip/hip_runtime.h>
#include <math.h>

#define H 64
#define NXCD 8
#define CH3 8192
#define CAP 4096
#define MAXCH 128

typedef __attribute__((ext_vector_type(8))) short short8;
typedef __attribute__((ext_vector_type(4))) float f32x4;

__device__ inline ushort f2bf(float f) {
    union { float f; unsigned u; } v;
    v.f = f;
    unsigned r = v.u + 0x7FFFu + ((v.u >> 16) & 1u);
    return (ushort)(r >> 16);
}

// ================= FAST PATH (3 kernels) =================

// ---------- Stage 1: chunk -> LDS bucket-sort -> static slab + run table ----------
// Chunk c owns bin2[c*CH3 ..]; zero global atomics. rofs/rlen[c][b] describe runs.
__global__ __launch_bounds__(1024) void k_bin_runs(const int* __restrict__ dst,
                                                   const int* __restrict__ src,
                                                   const float* __restrict__ t,
                                                   unsigned long long* __restrict__ bin2,
                                                   unsigned* __restrict__ rofs,
                                                   unsigned* __restrict__ rlen, int E) {
    __shared__ unsigned long long slab[CH3];
    __shared__ unsigned lcnt[1024];
    __shared__ unsigned lofs[1024];
    __shared__ unsigned wsum[16];
    int tid = threadIdx.x;
    int c = blockIdx.x;
    int e0 = c * CH3;
    int e1 = min(e0 + CH3, E);
    int cnt = e1 - e0;
    lcnt[tid] = 0;
    __syncthreads();
    for (int i = e0 + tid; i < e1; i += 1024) atomicAdd(&lcnt[dst[i] >> 8], 1u);
    __syncthreads();
    // exclusive scan of 1024 counters (verified pattern)
    unsigned v = lcnt[tid];
    int lane = tid & 63, w = tid >> 6;
    unsigned x = v;
#pragma unroll
    for (int off = 1; off < 64; off <<= 1) {
        unsigned y = __shfl_up(x, off, 64);
        if (lane >= off) x += y;
    }
    if (lane == 63) wsum[w] = x;
    __syncthreads();
    if (tid < 16) {
        unsigned s = wsum[tid];
#pragma unroll
        for (int off = 1; off < 16; off <<= 1) {
            unsigned y = __shfl_up(s, off, 16);
            if ((tid & 15) >= off) s += y;
        }
        wsum[tid] = s;
    }
    __syncthreads();
    unsigned excl = ((w > 0) ? wsum[w - 1] : 0u) + x - v;
    lofs[tid] = excl;
    rofs[(size_t)c * 1024 + tid] = (unsigned)e0 + excl;
    rlen[(size_t)c * 1024 + tid] = v;
    __syncthreads();
    lcnt[tid] = excl;  // running cursor
    __syncthreads();
    const float inv = 1.0f / (0.5f + 1e-8f);
    for (int i = e0 + tid; i < e1; i += 1024) {
        int d = dst[i];
        unsigned eb = f2bf(__expf(t[i] * inv));
        unsigned long long u = ((unsigned long long)d << 33)
                             | ((unsigned long long)src[i] << 16)
                             | (unsigned long long)eb;
        unsigned pos = atomicAdd(&lcnt[d >> 8], 1u);
        slab[pos] = u;
    }
    __syncthreads();
    for (int j = tid; j < cnt; j += 1024) bin2[e0 + j] = slab[j];
}

// ---------- Stage 2 (FUSED): run-table -> LDS CSR slab -> direct gather ----------
__global__ __launch_bounds__(1024) void k_fuse_runs(const unsigned* __restrict__ rofs,
                                                    const unsigned* __restrict__ rlen,
                                                    const unsigned long long* __restrict__ bin2,
                                                    const uint4* __restrict__ y4,
                                                    float* __restrict__ out,
                                                    int N, int nchunks) {
    __shared__ long long sPay[CAP];
    __shared__ unsigned lcnt[256];
    __shared__ unsigned lrel[257];
    __shared__ unsigned wsum[4];
    __shared__ unsigned rofsL[MAXCH];
    __shared__ unsigned rlenL[MAXCH];
    __shared__ unsigned rcum[MAXCH + 1];
    int b = blockIdx.x;
    int d0 = b << 8;
    int d1 = min(d0 + 256, N);
    int nd = d1 - d0;
    int tid = threadIdx.x;
    if (tid < nchunks) {
        rofsL[tid] = rofs[(size_t)tid * 1024 + b];
        rlenL[tid] = rlen[(size_t)tid * 1024 + b];
    }
    if (tid < 256) lcnt[tid] = 0;
    __syncthreads();
    if (tid == 0) {
        unsigned s = 0;
        for (int c = 0; c < nchunks; ++c) { rcum[c] = s; s += rlenL[c]; }
        rcum[nchunks] = s;
    }
    __syncthreads();
    int cnt = (int)rcum[nchunks];

    if (cnt > CAP) {
        // slow path (statistically never; deterministic): per-dst global walk
        int grp = tid >> 3, f = tid & 7;
        for (int ld = grp; ld < nd; ld += 128) {
            float acc[8] = {0.f, 0.f, 0.f, 0.f, 0.f, 0.f, 0.f, 0.f};
            float ssum = 0.f;
            for (int c = 0; c < nchunks; ++c) {
                unsigned ro = rofsL[c];
                int rl = (int)rlenL[c];
                for (int j = 0; j < rl; ++j) {
                    unsigned long long u = bin2[ro + j];
                    if ((int)(u >> 33) - d0 == ld) {
                        float e = __uint_as_float((unsigned)(u & 0xFFFFu) << 16);
                        int s = (int)((u >> 16) & 0x1FFFF);
                        ssum += e;
                        uint4 v = y4[(size_t)s * 8 + f];
                        acc[0] = fmaf(e, __uint_as_float(v.x << 16), acc[0]);
                        acc[1] = fmaf(e, __uint_as_float(v.x & 0xFFFF0000u), acc[1]);
                        acc[2] = fmaf(e, __uint_as_float(v.y << 16), acc[2]);
                        acc[3] = fmaf(e, __uint_as_float(v.y & 0xFFFF0000u), acc[3]);
                        acc[4] = fmaf(e, __uint_as_float(v.z << 16), acc[4]);
                        acc[5] = fmaf(e, __uint_as_float(v.z & 0xFFFF0000u), acc[5]);
                        acc[6] = fmaf(e, __uint_as_float(v.w << 16), acc[6]);
                        acc[7] = fmaf(e, __uint_as_float(v.w & 0xFFFF0000u), acc[7]);
                    }
                }
            }
            float rs = 1.0f / (ssum + 1e-16f);
            f32x4 o0 = {acc[0] * rs, acc[1] * rs, acc[2] * rs, acc[3] * rs};
            f32x4 o1 = {acc[4] * rs, acc[5] * rs, acc[6] * rs, acc[7] * rs};
            float* op = &out[(size_t)(d0 + ld) * H + f * 8];
            __builtin_nontemporal_store(o0, (f32x4*)op);
            __builtin_nontemporal_store(o1, (f32x4*)(op + 4));
        }
        return;
    }

    // Phase A1: count local dsts (flat index -> chunk via LDS binary search)
    for (int k = tid; k < cnt; k += 1024) {
        int lo = 0, hi = nchunks - 1;
        while (lo < hi) { int mid = (lo + hi + 1) >> 1; if ((int)rcum[mid] <= k) lo = mid; else hi = mid - 1; }
        unsigned long long u = bin2[rofsL[lo] + (unsigned)(k - (int)rcum[lo])];
        atomicAdd(&lcnt[(int)(u >> 33) - d0], 1u);
    }
    __syncthreads();
    // Phase A2: exclusive scan of 256 counters (verified R18 structure)
    if (tid < 256) {
        unsigned v = lcnt[tid];
        int lane = tid & 63, w = tid >> 6;
        unsigned x = v;
#pragma unroll
        for (int off = 1; off < 64; off <<= 1) {
            unsigned y = __shfl_up(x, off, 64);
            if (lane >= off) x += y;
        }
        if (lane == 63) wsum[w] = x;
        __syncthreads();
        if (tid == 0) {
            unsigned s = 0;
#pragma unroll
            for (int k = 0; k < 4; ++k) { unsigned tq = wsum[k]; wsum[k] = s; s += tq; }
        }
        __syncthreads();
        unsigned excl = wsum[w] + x - v;
        lrel[tid] = excl;
        lcnt[tid] = excl;
        if (tid == 0) lrel[256] = (unsigned)cnt;
    } else {
        __syncthreads();
        __syncthreads();
    }
    __syncthreads();
    // Phase A3: scatter entries into LDS slab (second read is L2-hot)
    for (int k = tid; k < cnt; k += 1024) {
        int lo = 0, hi = nchunks - 1;
        while (lo < hi) { int mid = (lo + hi + 1) >> 1; if ((int)rcum[mid] <= k) lo = mid; else hi = mid - 1; }
        unsigned long long u = bin2[rofsL[lo] + (unsigned)(k - (int)rcum[lo])];
        int d = (int)(u >> 33);
        int s = (int)((u >> 16) & 0x1FFFF);
        unsigned ef = (unsigned)(u & 0xFFFFu) << 16;
        unsigned lpos = atomicAdd(&lcnt[d - d0], 1u);
        sPay[lpos] = ((long long)(int)ef << 32) | (unsigned)s;
    }
    __syncthreads();
    // Phase B: gather. 128 groups of 8 lanes, 2 rounds over 256 dsts.
    int g = tid >> 3, f = tid & 7;
#pragma unroll
    for (int round = 0; round < 2; ++round) {
        int ld = round * 128 + g;
        if (ld >= nd) continue;
        int r0 = (int)lrel[ld];
        int r1 = (int)lrel[ld + 1];
        int deg = r1 - r0;
        float acc[8] = {0.f, 0.f, 0.f, 0.f, 0.f, 0.f, 0.f, 0.f};
        float ssum = 0.f;
        for (int it = 0; it < deg; it += 4) {
            float e[4];
            int s[4];
#pragma unroll
            for (int k2 = 0; k2 < 4; ++k2) {
                int pos = r0 + it + k2;
                bool ok = (it + k2) < deg;
                long long pl = sPay[ok ? pos : r0];
                e[k2] = ok ? __int_as_float((int)(pl >> 32)) : 0.f;
                s[k2] = ok ? (int)(pl & 0xFFFFFFFFll) : 0;
                ssum += e[k2];
            }
            uint4 v[4];
#pragma unroll
            for (int k2 = 0; k2 < 4; ++k2) v[k2] = y4[(size_t)s[k2] * 8 + f];
#pragma unroll
            for (int k2 = 0; k2 < 4; ++k2) {
                acc[0] = fmaf(e[k2], __uint_as_float(v[k2].x << 16), acc[0]);
                acc[1] = fmaf(e[k2], __uint_as_float(v[k2].x & 0xFFFF0000u), acc[1]);
                acc[2] = fmaf(e[k2], __uint_as_float(v[k2].y << 16), acc[2]);
                acc[3] = fmaf(e[k2], __uint_as_float(v[k2].y & 0xFFFF0000u), acc[3]);
                acc[4] = fmaf(e[k2], __uint_as_float(v[k2].z << 16), acc[4]);
                acc[5] = fmaf(e[k2], __uint_as_float(v[k2].z & 0xFFFF0000u), acc[5]);
                acc[6] = fmaf(e[k2], __uint_as_float(v[k2].w << 16), acc[6]);
                acc[7] = fmaf(e[k2], __uint_as_float(v[k2].w & 0xFFFF0000u), acc[7]);
            }
        }
        float rs = 1.0f / (ssum + 1e-16f);
        f32x4 o0 = {acc[0] * rs, acc[1] * rs, acc[2] * rs, acc[3] * rs};
        f32x4 o1 = {acc[4] * rs, acc[5] * rs, acc[6] * rs, acc[7] * rs};
        float* op = &out[(size_t)(d0 + ld) * H + f * 8];
        __builtin_nontemporal_store(o0, (f32x4*)op);
        __builtin_nontemporal_store(o1, (f32x4*)(op + 4));
    }
}

// ---------- Pre-transform: y(bf16) = x @ W^T via MFMA (verified R8) ----------
__global__ __launch_bounds__(256) void k_xform_mfma(const float* __restrict__ x,
                                                    const float* __restrict__ W,
                                                    ushort* __restrict__ y, int M) {
    int wid = (blockIdx.x * blockDim.x + threadIdx.x) >> 6;
    int lane = threadIdx.x & 63;
    int n0 = wid * 16;
    if (n0 >= M) return;
    int r = lane & 15, g = lane >> 4;

    short8 bfrag[4][2];
#pragma unroll
    for (int ct = 0; ct < 4; ++ct) {
#pragma unroll
        for (int kh = 0; kh < 2; ++kh) {
            const float* wp = &W[(size_t)(ct * 16 + r) * 64 + kh * 32 + g * 8];
            float4 w0 = *(const float4*)wp;
            float4 w1 = *(const float4*)(wp + 4);
            short8 bf;
            bf[0] = (short)f2bf(w0.x); bf[1] = (short)f2bf(w0.y);
            bf[2] = (short)f2bf(w0.z); bf[3] = (short)f2bf(w0.w);
            bf[4] = (short)f2bf(w1.x); bf[5] = (short)f2bf(w1.y);
            bf[6] = (short)f2bf(w1.z); bf[7] = (short)f2bf(w1.w);
            bfrag[ct][kh] = bf;
        }
    }
    int xr = n0 + r;
    if (xr >= M) xr = M - 1;
    const float* xp = &x[(size_t)xr * 64 + g * 8];
    short8 afrag[2];
#pragma unroll
    for (int kh = 0; kh < 2; ++kh) {
        float4 a0 = *(const float4*)(xp + kh * 32);
        float4 a1 = *(const float4*)(xp + kh * 32 + 4);
        short8 af;
        af[0] = (short)f2bf(a0.x); af[1] = (short)f2bf(a0.y);
        af[2] = (short)f2bf(a0.z); af[3] = (short)f2bf(a0.w);
        af[4] = (short)f2bf(a1.x); af[5] = (short)f2bf(a1.y);
        af[6] = (short)f2bf(a1.z); af[7] = (short)f2bf(a1.w);
        afrag[kh] = af;
    }
#pragma unroll
    for (int ct = 0; ct < 4; ++ct) {
        f32x4 acc = {0.f, 0.f, 0.f, 0.f};
        acc = __builtin_amdgcn_mfma_f32_16x16x32_bf16(afrag[0], bfrag[ct][0], acc, 0, 0, 0);
        acc = __builtin_amdgcn_mfma_f32_16x16x32_bf16(afrag[1], bfrag[ct][1], acc, 0, 0, 0);
#pragma unroll
        for (int q = 0; q < 4; ++q) {
            int row = n0 + g * 4 + q;
            if (row < M) y[(size_t)row * 64 + ct * 16 + r] = f2bf(acc[q]);
        }
    }
}

// ================= FALLBACK PATH (R10-proven) =================

__global__ void k_hist(const int* __restrict__ dst, unsigned* __restrict__ cnt, int E) {
    int i = blockIdx.x * blockDim.x + threadIdx.x;
    int st = gridDim.x * blockDim.x;
    int E4 = E >> 2;
    const int4* d4 = (const int4*)dst;
    for (int k = i; k < E4; k += st) {
        int4 v = d4[k];
        atomicAdd(&cnt[v.x], 1u);
        atomicAdd(&cnt[v.y], 1u);
        atomicAdd(&cnt[v.z], 1u);
        atomicAdd(&cnt[v.w], 1u);
    }
    for (int k = (E4 << 2) + i; k < E; k += st) atomicAdd(&cnt[dst[k]], 1u);
}

__global__ __launch_bounds__(1024) void k_scanA(const unsigned* __restrict__ cnt,
                                                unsigned* __restrict__ base,
                                                unsigned* __restrict__ bsum, int N) {
    __shared__ unsigned wsum[16];
    int i = blockIdx.x * 1024 + threadIdx.x;
    unsigned v = (i < N) ? cnt[i] : 0u;
    int lane = threadIdx.x & 63, w = threadIdx.x >> 6;
    unsigned x = v;
#pragma unroll
    for (int off = 1; off < 64; off <<= 1) {
        unsigned y = __shfl_up(x, off, 64);
        if (lane >= off) x += y;
    }
    if (lane == 63) wsum[w] = x;
    __syncthreads();
    if (threadIdx.x < 16) {
        unsigned s = wsum[threadIdx.x];
#pragma unroll
        for (int off = 1; off < 16; off <<= 1) {
            unsigned y = __shfl_up(s, off, 16);
            if ((threadIdx.x & 15) >= off) s += y;
        }
        wsum[threadIdx.x] = s;
    }
    __syncthreads();
    unsigned wbase = (w > 0) ? wsum[w - 1] : 0u;
    if (i < N) base[i] = wbase + x - v;
    if (threadIdx.x == 1023) bsum[blockIdx.x] = wsum[15];
}

__global__ __launch_bounds__(1024) void k_scanB(const unsigned* __restrict__ bsum,
                                                unsigned* __restrict__ boff, int nb) {
    __shared__ unsigned wsum[16];
    int i = threadIdx.x;
    unsigned v = (i < nb) ? bsum[i] : 0u;
    int lane = i & 63, w = i >> 6;
    unsigned x = v;
#pragma unroll
    for (int off = 1; off < 64; off <<= 1) {
        unsigned y = __shfl_up(x, off, 64);
        if (lane >= off) x += y;
    }
    if (lane == 63) wsum[w] = x;
    __syncthreads();
    if (i < 16) {
        unsigned s = wsum[i];
#pragma unroll
        for (int off = 1; off < 16; off <<= 1) {
            unsigned y = __shfl_up(s, off, 16);
            if ((i & 15) >= off) s += y;
        }
        wsum[i] = s;
    }
    __syncthreads();
    unsigned wbase = (w > 0) ? wsum[w - 1] : 0u;
    if (i < nb) boff[i] = wbase + x - v;
}

__global__ void k_scanC(unsigned* __restrict__ base, unsigned* __restrict__ cursor,
                        const unsigned* __restrict__ boff, int N, int E) {
    int i = blockIdx.x * blockDim.x + threadIdx.x;
    int st = gridDim.x * blockDim.x;
    for (; i < N; i += st) {
        unsigned b = base[i] + boff[i >> 10];
        base[i] = b;
        cursor[i] = b;
    }
    if (blockIdx.x == 0 && threadIdx.x == 0) base[N] = (unsigned)E;
}

__global__ void k_permute_part(const int* __restrict__ dst, const int* __restrict__ src,
                               const float* __restrict__ t, unsigned* __restrict__ cursor,
                               int2* __restrict__ payload, int E, int N) {
    const float inv = 1.0f / (0.5f + 1e-8f);
    int part = blockIdx.x & (NXCD - 1);
    int nslice = gridDim.x >> 3;
    int sblk = blockIdx.x >> 3;
    int lo = (int)((long long)part * N / NXCD);
    int hi = (int)((long long)(part + 1) * N / NXCD);
    int e0 = (int)((long long)sblk * E / nslice);
    int e1 = (int)((long long)(sblk + 1) * E / nslice);
    for (int i = e0 + threadIdx.x; i < e1; i += blockDim.x) {
        int d = dst[i];
        if (d >= lo && d < hi) {
            unsigned pos = atomicAdd(&cursor[d], 1u);
            float e = __expf(t[i] * inv);
            payload[pos] = make_int2(src[i], __float_as_int(e));
        }
    }
}

__global__ void k_permute_pack(const int* __restrict__ dst, const int* __restrict__ src,
                               const float* __restrict__ t, unsigned* __restrict__ cursor,
                               int2* __restrict__ payload, int E) {
    const float inv = 1.0f / (0.5f + 1e-8f);
    int i = blockIdx.x * blockDim.x + threadIdx.x;
    int st = gridDim.x * blockDim.x;
    for (; i < E; i += st) {
        unsigned pos = atomicAdd(&cursor[dst[i]], 1u);
        float e = __expf(t[i] * inv);
        payload[pos] = make_int2(src[i], __float_as_int(e));
    }
}

__global__ __launch_bounds__(256) void k_gather4(const unsigned* __restrict__ base,
                                                 const long long* __restrict__ payload,
                                                 const uint2* __restrict__ y2,
                                                 float* __restrict__ out, int N) {
    int tid = blockIdx.x * blockDim.x + threadIdx.x;
    int lane = threadIdx.x & 63;
    int g = lane >> 4, f = lane & 15;
    int d = (tid >> 6) * 4 + g;
    if (d >= N) return;
    unsigned r0 = base[d], r1 = base[d + 1];
    int deg = (int)(r1 - r0);
    float acc0 = 0.f, acc1 = 0.f, acc2 = 0.f, acc3 = 0.f, ssum = 0.f;
    for (int it = 0; it < deg; it += 4) {
        float e[4];
        int s[4];
#pragma unroll
        for (int k2 = 0; k2 < 4; ++k2) {
            long long pl = __builtin_nontemporal_load(&payload[r0 + it + k2]);
            bool ok = (it + k2) < deg;
            e[k2] = ok ? __int_as_float((int)(pl >> 32)) : 0.f;
            s[k2] = ok ? (int)(pl & 0xFFFFFFFFll) : 0;
            ssum += e[k2];
        }
        uint2 v[4];
#pragma unroll
        for (int k2 = 0; k2 < 4; ++k2) v[k2] = y2[(size_t)s[k2] * 16 + f];
#pragma unroll
        for (int k2 = 0; k2 < 4; ++k2) {
            acc0 = fmaf(e[k2], __uint_as_float(v[k2].x << 16), acc0);
            acc1 = fmaf(e[k2], __uint_as_float(v[k2].x & 0xFFFF0000u), acc1);
            acc2 = fmaf(e[k2], __uint_as_float(v[k2].y << 16), acc2);
            acc3 = fmaf(e[k2], __uint_as_float(v[k2].y & 0xFFFF0000u), acc3);
        }
    }
    float rs = 1.0f / (ssum + 1e-16f);
    f32x4 o = {acc0 * rs, acc1 * rs, acc2 * rs, acc3 * rs};
    __builtin_nontemporal_store(o, (f32x4*)&out[(size_t)d * H + f * 4]);
}

__global__ __launch_bounds__(256) void k_gather_fb(const unsigned* __restrict__ base,
                                                   const int2* __restrict__ payload,
                                                   const float* __restrict__ x_src,
                                                   const float* __restrict__ W,
                                                   float* __restrict__ out, int N) {
    __shared__ float wt[H * H];
    for (int idx = threadIdx.x; idx < H * H; idx += blockDim.x) {
        int j = idx >> 6, k = idx & 63;
        wt[k * H + j] = W[idx];
    }
    __syncthreads();
    int lane = threadIdx.x & 63;
    int wid = (blockIdx.x * blockDim.x + threadIdx.x) >> 6;
    int nw = (gridDim.x * blockDim.x) >> 6;
    for (int d = wid; d < N; d += nw) {
        unsigned r0 = base[d], r1 = base[d + 1];
        int deg = (int)(r1 - r0);
        float acc = 0.0f, ssum = 0.0f;
        for (int c = 0; c < deg; c += 64) {
            int j = c + lane;
            int cd = min(64, deg - c);
            float e = 0.0f;
            int sidx = 0;
            if (j < deg) {
                int2 p = payload[r0 + j];
                sidx = p.x;
                e = __int_as_float(p.y);
            }
            float cs = e;
#pragma unroll
            for (int off = 32; off >= 1; off >>= 1) cs += __shfl_xor(cs, off, 64);
            ssum += cs;
            for (int q = 0; q < cd; q += 8) {
                float a[8];
                int sv[8];
                float v[8];
#pragma unroll
                for (int u = 0; u < 8; ++u) {
                    a[u] = __shfl(e, q + u, 64);
                    sv[u] = __shfl(sidx, q + u, 64);
                }
#pragma unroll
                for (int u = 0; u < 8; ++u) v[u] = x_src[(size_t)sv[u] * H + lane];
#pragma unroll
                for (int u = 0; u < 8; ++u) acc = fmaf(a[u], v[u], acc);
            }
        }
        acc *= 1.0f / (ssum + 1e-16f);
        float o = 0.0f;
#pragma unroll
        for (int k = 0; k < H; ++k) o = fmaf(__shfl(acc, k, 64), wt[k * H + lane], o);
        out[(size_t)d * H + lane] = o;
    }
}

extern "C" void kernel_launch(void* const* d_in, const int* in_sizes, int n_in,
                              void* d_out, int out_size, void* d_ws, size_t ws_size,
                              hipStream_t stream) {
    const float* x_src = (const float*)d_in[0];
    const float* W = (const float*)d_in[2];
    const int* edge_index = (const int*)d_in[3];
    const float* t = (const float*)d_in[4];

    int E = in_sizes[4];
    int N = in_sizes[1] / H;  // N_DST
    int M = in_sizes[0] / H;  // N_SRC
    const int* src = edge_index;
    const int* dst = edge_index + E;

    // head layout kept identical to R19 (fallback paths depend on it)
    unsigned* base = (unsigned*)d_ws;
    unsigned* cursor = base + (size_t)N + 1;
    unsigned* bsum = cursor + N;
    unsigned* boff = bsum + 1024;
    size_t head_u32 = (size_t)(2 * N + 1) + 1024 + 1024 + 32 + 1024 + 1056 + 1056;
    size_t pay_off = (head_u32 * 4 + 15) & ~(size_t)15;
    int2* payload = (int2*)((char*)d_ws + pay_off);

    // fast-path layout: run tables live in the old payload region
    int nchunks = (E + CH3 - 1) / CH3;
    size_t bin2_entries = (size_t)nchunks * CH3;
    unsigned* rofs = (unsigned*)((char*)d_ws + pay_off);
    unsigned* rlen = rofs + (size_t)MAXCH * 1024;
    size_t b2_off = (pay_off + (size_t)MAXCH * 1024 * 8 + 15) & ~(size_t)15;
    unsigned long long* bin2 = (unsigned long long*)((char*)d_ws + b2_off);
    size_t yf_off = b2_off + bin2_entries * 8;
    ushort* y = (ushort*)((char*)d_ws + yf_off);

    bool packable = (M < (1 << 17)) && (N < (1 << 17));
    int NB = (N + 255) >> 8;
    bool have_fast = (ws_size >= yf_off + (size_t)M * H * 2) && packable &&
                     (NB <= 1024) && (nchunks <= MAXCH);
    bool have_y_small = (ws_size >= pay_off + (size_t)E * 8 + (size_t)M * H * 2 + 32);

    int nb = (N + 1023) / 1024;
    int blocks_e = (E + 255) / 256;
    if (blocks_e > 2048) blocks_e = 2048;

    if (have_fast) {
        int xblocks = ((M + 15) / 16 * 64 + 255) / 256;
        k_xform_mfma<<<xblocks, 256, 0, stream>>>(x_src, W, y, M);
        k_bin_runs<<<nchunks, 1024, 0, stream>>>(dst, src, t, bin2, rofs, rlen, E);
        k_fuse_runs<<<NB, 1024, 0, stream>>>(rofs, rlen, bin2, (const uint4*)y,
                                             (float*)d_out, N, nchunks);
    } else if (have_y_small) {
        ushort* y2p = (ushort*)((char*)d_ws + pay_off + (size_t)E * 8);
        hipMemsetAsync(cursor, 0, (size_t)N * sizeof(unsigned), stream);
        k_hist<<<1024, 256, 0, stream>>>(dst, cursor, E);
        k_scanA<<<nb, 1024, 0, stream>>>(cursor, base, bsum, N);
        k_scanB<<<1, 1024, 0, stream>>>(bsum, boff, nb);
        k_scanC<<<512, 256, 0, stream>>>(base, cursor, boff, N, E);
        int xblocks = ((M + 15) / 16 * 64 + 255) / 256;
        k_xform_mfma<<<xblocks, 256, 0, stream>>>(x_src, W, y2p, M);
        k_permute_part<<<2048, 256, 0, stream>>>(dst, src, t, cursor, payload, E, N);
        int gblocks = (N + 15) / 16;
        k_gather4<<<gblocks, 256, 0, stream>>>(base, (const long long*)payload,
                                               (const uint2*)y2p, (float*)d_out, N);
    } else {
        hipMemsetAsync(cursor, 0, (size_t)N * sizeof(unsigned), stream);
        k_hist<<<1024, 256, 0, stream>>>(dst, cursor, E);
        k_scanA<<<nb, 1024, 0, stream>>>(cursor, base, bsum, N);
        k_scanB<<<1, 1024, 0, stream>>>(bsum, boff, nb);
        k_scanC<<<512, 256, 0, stream>>>(base, cursor, boff, N, E);
        k_permute_pack<<<blocks_e, 256, 0, stream>>>(dst, src, t, cursor, payload, E);
        k_gather_fb<<<4096, 256, 0, stream>>>(base, payload, x_src, W, (float*)d_out, N);
    }
}

// Round 21
// 73.416 us; speedup vs baseline: 1.8622x; 1.0003x over previous
//
#include <hip/hip_runtime.h>
#include <math.h>

#define H 64
#define NXCD 8
#define CH3 8192
#define CAP 4096
#define MAXCH 128

typedef __attribute__((ext_vector_type(8))) short short8;
typedef __attribute__((ext_vector_type(4))) float f32x4;

__device__ inline ushort f2bf(float f) {
    union { float f; unsigned u; } v;
    v.f = f;
    unsigned r = v.u + 0x7FFFu + ((v.u >> 16) & 1u);
    return (ushort)(r >> 16);
}

// ================= FAST PATH (2 kernels) =================

// ---------- Stage 1 (MERGED): bin chunks + xform tiles in one dispatch ----------
// Blocks [0, nchunks): chunk -> LDS bucket-sort -> static slab + run table (R19-verified).
// Blocks [nchunks, nchunks+xb): y(bf16) = x @ W^T via MFMA, 16 waves x 16 rows (R8-verified).
// The two phases are data-independent; merging overlaps their memory streams.
__global__ __launch_bounds__(1024) void k_prep(const float* __restrict__ x,
                                               const float* __restrict__ W,
                                               ushort* __restrict__ y, int M,
                                               const int* __restrict__ dst,
                                               const int* __restrict__ src,
                                               const float* __restrict__ t,
                                               unsigned long long* __restrict__ bin2,
                                               unsigned* __restrict__ rofs,
                                               unsigned* __restrict__ rlen,
                                               int E, int nchunks) {
    __shared__ unsigned long long slab[CH3];
    __shared__ unsigned lcnt[1024];
    __shared__ unsigned wsum[16];
    int tid = threadIdx.x;
    if ((int)blockIdx.x < nchunks) {
        // ----- bin_runs body (verified R19/R20) -----
        int c = blockIdx.x;
        int e0 = c * CH3;
        int e1 = min(e0 + CH3, E);
        int cnt = e1 - e0;
        lcnt[tid] = 0;
        __syncthreads();
        for (int i = e0 + tid; i < e1; i += 1024) atomicAdd(&lcnt[dst[i] >> 8], 1u);
        __syncthreads();
        unsigned v = lcnt[tid];
        int lane = tid & 63, w = tid >> 6;
        unsigned xx = v;
#pragma unroll
        for (int off = 1; off < 64; off <<= 1) {
            unsigned yv = __shfl_up(xx, off, 64);
            if (lane >= off) xx += yv;
        }
        if (lane == 63) wsum[w] = xx;
        __syncthreads();
        if (tid < 16) {
            unsigned s = wsum[tid];
#pragma unroll
            for (int off = 1; off < 16; off <<= 1) {
                unsigned yv = __shfl_up(s, off, 16);
                if ((tid & 15) >= off) s += yv;
            }
            wsum[tid] = s;
        }
        __syncthreads();
        unsigned excl = ((w > 0) ? wsum[w - 1] : 0u) + xx - v;
        rofs[(size_t)c * 1024 + tid] = (unsigned)e0 + excl;
        rlen[(size_t)c * 1024 + tid] = v;
        __syncthreads();
        lcnt[tid] = excl;  // running cursor
        __syncthreads();
        const float inv = 1.0f / (0.5f + 1e-8f);
        for (int i = e0 + tid; i < e1; i += 1024) {
            int d = dst[i];
            unsigned eb = f2bf(__expf(t[i] * inv));
            unsigned long long u = ((unsigned long long)d << 33)
                                 | ((unsigned long long)src[i] << 16)
                                 | (unsigned long long)eb;
            unsigned pos = atomicAdd(&lcnt[d >> 8], 1u);
            slab[pos] = u;
        }
        __syncthreads();
        for (int j = tid; j < cnt; j += 1024) bin2[e0 + j] = slab[j];
    } else {
        // ----- xform body (verified R8), 16 waves x 16-row tiles -----
        int wid = ((int)blockIdx.x - nchunks) * 16 + (tid >> 6);
        int lane = tid & 63;
        int n0 = wid * 16;
        if (n0 >= M) return;
        int r = lane & 15, g = lane >> 4;
        short8 bfrag[4][2];
#pragma unroll
        for (int ct = 0; ct < 4; ++ct) {
#pragma unroll
            for (int kh = 0; kh < 2; ++kh) {
                const float* wp = &W[(size_t)(ct * 16 + r) * 64 + kh * 32 + g * 8];
                float4 w0 = *(const float4*)wp;
                float4 w1 = *(const float4*)(wp + 4);
                short8 bf;
                bf[0] = (short)f2bf(w0.x); bf[1] = (short)f2bf(w0.y);
                bf[2] = (short)f2bf(w0.z); bf[3] = (short)f2bf(w0.w);
                bf[4] = (short)f2bf(w1.x); bf[5] = (short)f2bf(w1.y);
                bf[6] = (short)f2bf(w1.z); bf[7] = (short)f2bf(w1.w);
                bfrag[ct][kh] = bf;
            }
        }
        int xr = n0 + r;
        if (xr >= M) xr = M - 1;
        const float* xp = &x[(size_t)xr * 64 + g * 8];
        short8 afrag[2];
#pragma unroll
        for (int kh = 0; kh < 2; ++kh) {
            float4 a0 = *(const float4*)(xp + kh * 32);
            float4 a1 = *(const float4*)(xp + kh * 32 + 4);
            short8 af;
            af[0] = (short)f2bf(a0.x); af[1] = (short)f2bf(a0.y);
            af[2] = (short)f2bf(a0.z); af[3] = (short)f2bf(a0.w);
            af[4] = (short)f2bf(a1.x); af[5] = (short)f2bf(a1.y);
            af[6] = (short)f2bf(a1.z); af[7] = (short)f2bf(a1.w);
            afrag[kh] = af;
        }
#pragma unroll
        for (int ct = 0; ct < 4; ++ct) {
            f32x4 acc = {0.f, 0.f, 0.f, 0.f};
            acc = __builtin_amdgcn_mfma_f32_16x16x32_bf16(afrag[0], bfrag[ct][0], acc, 0, 0, 0);
            acc = __builtin_amdgcn_mfma_f32_16x16x32_bf16(afrag[1], bfrag[ct][1], acc, 0, 0, 0);
#pragma unroll
            for (int q = 0; q < 4; ++q) {
                int row = n0 + g * 4 + q;
                if (row < M) y[(size_t)row * 64 + ct * 16 + r] = f2bf(acc[q]);
            }
        }
    }
}

// ---------- Stage 2 (FUSED): run-table -> LDS CSR slab -> direct gather (verified R20) ----------
__global__ __launch_bounds__(1024) void k_fuse_runs(const unsigned* __restrict__ rofs,
                                                    const unsigned* __restrict__ rlen,
                                                    const unsigned long long* __restrict__ bin2,
                                                    const uint4* __restrict__ y4,
                                                    float* __restrict__ out,
                                                    int N, int nchunks) {
    __shared__ long long sPay[CAP];
    __shared__ unsigned lcnt[256];
    __shared__ unsigned lrel[257];
    __shared__ unsigned wsum[4];
    __shared__ unsigned rofsL[MAXCH];
    __shared__ unsigned rlenL[MAXCH];
    __shared__ unsigned rcum[MAXCH + 1];
    int b = blockIdx.x;
    int d0 = b << 8;
    int d1 = min(d0 + 256, N);
    int nd = d1 - d0;
    int tid = threadIdx.x;
    if (tid < nchunks) {
        rofsL[tid] = rofs[(size_t)tid * 1024 + b];
        rlenL[tid] = rlen[(size_t)tid * 1024 + b];
    }
    if (tid < 256) lcnt[tid] = 0;
    __syncthreads();
    if (tid == 0) {
        unsigned s = 0;
        for (int c = 0; c < nchunks; ++c) { rcum[c] = s; s += rlenL[c]; }
        rcum[nchunks] = s;
    }
    __syncthreads();
    int cnt = (int)rcum[nchunks];

    if (cnt > CAP) {
        // slow path (statistically never; deterministic): per-dst global walk
        int grp = tid >> 3, f = tid & 7;
        for (int ld = grp; ld < nd; ld += 128) {
            float acc[8] = {0.f, 0.f, 0.f, 0.f, 0.f, 0.f, 0.f, 0.f};
            float ssum = 0.f;
            for (int c = 0; c < nchunks; ++c) {
                unsigned ro = rofsL[c];
                int rl = (int)rlenL[c];
                for (int j = 0; j < rl; ++j) {
                    unsigned long long u = bin2[ro + j];
                    if ((int)(u >> 33) - d0 == ld) {
                        float e = __uint_as_float((unsigned)(u & 0xFFFFu) << 16);
                        int s = (int)((u >> 16) & 0x1FFFF);
                        ssum += e;
                        uint4 v = y4[(size_t)s * 8 + f];
                        acc[0] = fmaf(e, __uint_as_float(v.x << 16), acc[0]);
                        acc[1] = fmaf(e, __uint_as_float(v.x & 0xFFFF0000u), acc[1]);
                        acc[2] = fmaf(e, __uint_as_float(v.y << 16), acc[2]);
                        acc[3] = fmaf(e, __uint_as_float(v.y & 0xFFFF0000u), acc[3]);
                        acc[4] = fmaf(e, __uint_as_float(v.z << 16), acc[4]);
                        acc[5] = fmaf(e, __uint_as_float(v.z & 0xFFFF0000u), acc[5]);
                        acc[6] = fmaf(e, __uint_as_float(v.w << 16), acc[6]);
                        acc[7] = fmaf(e, __uint_as_float(v.w & 0xFFFF0000u), acc[7]);
                    }
                }
            }
            float rs = 1.0f / (ssum + 1e-16f);
            f32x4 o0 = {acc[0] * rs, acc[1] * rs, acc[2] * rs, acc[3] * rs};
            f32x4 o1 = {acc[4] * rs, acc[5] * rs, acc[6] * rs, acc[7] * rs};
            float* op = &out[(size_t)(d0 + ld) * H + f * 8];
            __builtin_nontemporal_store(o0, (f32x4*)op);
            __builtin_nontemporal_store(o1, (f32x4*)(op + 4));
        }
        return;
    }

    // Phase A1: count local dsts (flat index -> chunk via LDS binary search)
    for (int k = tid; k < cnt; k += 1024) {
        int lo = 0, hi = nchunks - 1;
        while (lo < hi) { int mid = (lo + hi + 1) >> 1; if ((int)rcum[mid] <= k) lo = mid; else hi = mid - 1; }
        unsigned long long u = bin2[rofsL[lo] + (unsigned)(k - (int)rcum[lo])];
        atomicAdd(&lcnt[(int)(u >> 33) - d0], 1u);
    }
    __syncthreads();
    // Phase A2: exclusive scan of 256 counters
    if (tid < 256) {
        unsigned v = lcnt[tid];
        int lane = tid & 63, w = tid >> 6;
        unsigned x = v;
#pragma unroll
        for (int off = 1; off < 64; off <<= 1) {
            unsigned y = __shfl_up(x, off, 64);
            if (lane >= off) x += y;
        }
        if (lane == 63) wsum[w] = x;
        __syncthreads();
        if (tid == 0) {
            unsigned s = 0;
#pragma unroll
            for (int k = 0; k < 4; ++k) { unsigned tq = wsum[k]; wsum[k] = s; s += tq; }
        }
        __syncthreads();
        unsigned excl = wsum[w] + x - v;
        lrel[tid] = excl;
        lcnt[tid] = excl;
        if (tid == 0) lrel[256] = (unsigned)cnt;
    } else {
        __syncthreads();
        __syncthreads();
    }
    __syncthreads();
    // Phase A3: scatter entries into LDS slab (second read is L2-hot)
    for (int k = tid; k < cnt; k += 1024) {
        int lo = 0, hi = nchunks - 1;
        while (lo < hi) { int mid = (lo + hi + 1) >> 1; if ((int)rcum[mid] <= k) lo = mid; else hi = mid - 1; }
        unsigned long long u = bin2[rofsL[lo] + (unsigned)(k - (int)rcum[lo])];
        int d = (int)(u >> 33);
        int s = (int)((u >> 16) & 0x1FFFF);
        unsigned ef = (unsigned)(u & 0xFFFFu) << 16;
        unsigned lpos = atomicAdd(&lcnt[d - d0], 1u);
        sPay[lpos] = ((long long)(int)ef << 32) | (unsigned)s;
    }
    __syncthreads();
    // Phase B: gather. 128 groups of 8 lanes, 2 rounds over 256 dsts.
    int g = tid >> 3, f = tid & 7;
#pragma unroll
    for (int round = 0; round < 2; ++round) {
        int ld = round * 128 + g;
        if (ld >= nd) continue;
        int r0 = (int)lrel[ld];
        int r1 = (int)lrel[ld + 1];
        int deg = r1 - r0;
        float acc[8] = {0.f, 0.f, 0.f, 0.f, 0.f, 0.f, 0.f, 0.f};
        float ssum = 0.f;
        for (int it = 0; it < deg; it += 4) {
            float e[4];
            int s[4];
#pragma unroll
            for (int k2 = 0; k2 < 4; ++k2) {
                int pos = r0 + it + k2;
                bool ok = (it + k2) < deg;
                long long pl = sPay[ok ? pos : r0];
                e[k2] = ok ? __int_as_float((int)(pl >> 32)) : 0.f;
                s[k2] = ok ? (int)(pl & 0xFFFFFFFFll) : 0;
                ssum += e[k2];
            }
            uint4 v[4];
#pragma unroll
            for (int k2 = 0; k2 < 4; ++k2) v[k2] = y4[(size_t)s[k2] * 8 + f];
#pragma unroll
            for (int k2 = 0; k2 < 4; ++k2) {
                acc[0] = fmaf(e[k2], __uint_as_float(v[k2].x << 16), acc[0]);
                acc[1] = fmaf(e[k2], __uint_as_float(v[k2].x & 0xFFFF0000u), acc[1]);
                acc[2] = fmaf(e[k2], __uint_as_float(v[k2].y << 16), acc[2]);
                acc[3] = fmaf(e[k2], __uint_as_float(v[k2].y & 0xFFFF0000u), acc[3]);
                acc[4] = fmaf(e[k2], __uint_as_float(v[k2].z << 16), acc[4]);
                acc[5] = fmaf(e[k2], __uint_as_float(v[k2].z & 0xFFFF0000u), acc[5]);
                acc[6] = fmaf(e[k2], __uint_as_float(v[k2].w << 16), acc[6]);
                acc[7] = fmaf(e[k2], __uint_as_float(v[k2].w & 0xFFFF0000u), acc[7]);
            }
        }
        float rs = 1.0f / (ssum + 1e-16f);
        f32x4 o0 = {acc[0] * rs, acc[1] * rs, acc[2] * rs, acc[3] * rs};
        f32x4 o1 = {acc[4] * rs, acc[5] * rs, acc[6] * rs, acc[7] * rs};
        float* op = &out[(size_t)(d0 + ld) * H + f * 8];
        __builtin_nontemporal_store(o0, (f32x4*)op);
        __builtin_nontemporal_store(o1, (f32x4*)(op + 4));
    }
}

// ---------- Standalone xform (fallback paths) ----------
__global__ __launch_bounds__(256) void k_xform_mfma(const float* __restrict__ x,
                                                    const float* __restrict__ W,
                                                    ushort* __restrict__ y, int M) {
    int wid = (blockIdx.x * blockDim.x + threadIdx.x) >> 6;
    int lane = threadIdx.x & 63;
    int n0 = wid * 16;
    if (n0 >= M) return;
    int r = lane & 15, g = lane >> 4;
    short8 bfrag[4][2];
#pragma unroll
    for (int ct = 0; ct < 4; ++ct) {
#pragma unroll
        for (int kh = 0; kh < 2; ++kh) {
            const float* wp = &W[(size_t)(ct * 16 + r) * 64 + kh * 32 + g * 8];
            float4 w0 = *(const float4*)wp;
            float4 w1 = *(const float4*)(wp + 4);
            short8 bf;
            bf[0] = (short)f2bf(w0.x); bf[1] = (short)f2bf(w0.y);
            bf[2] = (short)f2bf(w0.z); bf[3] = (short)f2bf(w0.w);
            bf[4] = (short)f2bf(w1.x); bf[5] = (short)f2bf(w1.y);
            bf[6] = (short)f2bf(w1.z); bf[7] = (short)f2bf(w1.w);
            bfrag[ct][kh] = bf;
        }
    }
    int xr = n0 + r;
    if (xr >= M) xr = M - 1;
    const float* xp = &x[(size_t)xr * 64 + g * 8];
    short8 afrag[2];
#pragma unroll
    for (int kh = 0; kh < 2; ++kh) {
        float4 a0 = *(const float4*)(xp + kh * 32);
        float4 a1 = *(const float4*)(xp + kh * 32 + 4);
        short8 af;
        af[0] = (short)f2bf(a0.x); af[1] = (short)f2bf(a0.y);
        af[2] = (short)f2bf(a0.z); af[3] = (short)f2bf(a0.w);
        af[4] = (short)f2bf(a1.x); af[5] = (short)f2bf(a1.y);
        af[6] = (short)f2bf(a1.z); af[7] = (short)f2bf(a1.w);
        afrag[kh] = af;
    }
#pragma unroll
    for (int ct = 0; ct < 4; ++ct) {
        f32x4 acc = {0.f, 0.f, 0.f, 0.f};
        acc = __builtin_amdgcn_mfma_f32_16x16x32_bf16(afrag[0], bfrag[ct][0], acc, 0, 0, 0);
        acc = __builtin_amdgcn_mfma_f32_16x16x32_bf16(afrag[1], bfrag[ct][1], acc, 0, 0, 0);
#pragma unroll
        for (int q = 0; q < 4; ++q) {
            int row = n0 + g * 4 + q;
            if (row < M) y[(size_t)row * 64 + ct * 16 + r] = f2bf(acc[q]);
        }
    }
}

// ================= FALLBACK PATH (R10-proven) =================

__global__ void k_hist(const int* __restrict__ dst, unsigned* __restrict__ cnt, int E) {
    int i = blockIdx.x * blockDim.x + threadIdx.x;
    int st = gridDim.x * blockDim.x;
    int E4 = E >> 2;
    const int4* d4 = (const int4*)dst;
    for (int k = i; k < E4; k += st) {
        int4 v = d4[k];
        atomicAdd(&cnt[v.x], 1u);
        atomicAdd(&cnt[v.y], 1u);
        atomicAdd(&cnt[v.z], 1u);
        atomicAdd(&cnt[v.w], 1u);
    }
    for (int k = (E4 << 2) + i; k < E; k += st) atomicAdd(&cnt[dst[k]], 1u);
}

__global__ __launch_bounds__(1024) void k_scanA(const unsigned* __restrict__ cnt,
                                                unsigned* __restrict__ base,
                                                unsigned* __restrict__ bsum, int N) {
    __shared__ unsigned wsum[16];
    int i = blockIdx.x * 1024 + threadIdx.x;
    unsigned v = (i < N) ? cnt[i] : 0u;
    int lane = threadIdx.x & 63, w = threadIdx.x >> 6;
    unsigned x = v;
#pragma unroll
    for (int off = 1; off < 64; off <<= 1) {
        unsigned y = __shfl_up(x, off, 64);
        if (lane >= off) x += y;
    }
    if (lane == 63) wsum[w] = x;
    __syncthreads();
    if (threadIdx.x < 16) {
        unsigned s = wsum[threadIdx.x];
#pragma unroll
        for (int off = 1; off < 16; off <<= 1) {
            unsigned y = __shfl_up(s, off, 16);
            if ((threadIdx.x & 15) >= off) s += y;
        }
        wsum[threadIdx.x] = s;
    }
    __syncthreads();
    unsigned wbase = (w > 0) ? wsum[w - 1] : 0u;
    if (i < N) base[i] = wbase + x - v;
    if (threadIdx.x == 1023) bsum[blockIdx.x] = wsum[15];
}

__global__ __launch_bounds__(1024) void k_scanB(const unsigned* __restrict__ bsum,
                                                unsigned* __restrict__ boff, int nb) {
    __shared__ unsigned wsum[16];
    int i = threadIdx.x;
    unsigned v = (i < nb) ? bsum[i] : 0u;
    int lane = i & 63, w = i >> 6;
    unsigned x = v;
#pragma unroll
    for (int off = 1; off < 64; off <<= 1) {
        unsigned y = __shfl_up(x, off, 64);
        if (lane >= off) x += y;
    }
    if (lane == 63) wsum[w] = x;
    __syncthreads();
    if (i < 16) {
        unsigned s = wsum[i];
#pragma unroll
        for (int off = 1; off < 16; off <<= 1) {
            unsigned y = __shfl_up(s, off, 16);
            if ((i & 15) >= off) s += y;
        }
        wsum[i] = s;
    }
    __syncthreads();
    unsigned wbase = (w > 0) ? wsum[w - 1] : 0u;
    if (i < nb) boff[i] = wbase + x - v;
}

__global__ void k_scanC(unsigned* __restrict__ base, unsigned* __restrict__ cursor,
                        const unsigned* __restrict__ boff, int N, int E) {
    int i = blockIdx.x * blockDim.x + threadIdx.x;
    int st = gridDim.x * blockDim.x;
    for (; i < N; i += st) {
        unsigned b = base[i] + boff[i >> 10];
        base[i] = b;
        cursor[i] = b;
    }
    if (blockIdx.x == 0 && threadIdx.x == 0) base[N] = (unsigned)E;
}

__global__ void k_permute_part(const int* __restrict__ dst, const int* __restrict__ src,
                               const float* __restrict__ t, unsigned* __restrict__ cursor,
                               int2* __restrict__ payload, int E, int N) {
    const float inv = 1.0f / (0.5f + 1e-8f);
    int part = blockIdx.x & (NXCD - 1);
    int nslice = gridDim.x >> 3;
    int sblk = blockIdx.x >> 3;
    int lo = (int)((long long)part * N / NXCD);
    int hi = (int)((long long)(part + 1) * N / NXCD);
    int e0 = (int)((long long)sblk * E / nslice);
    int e1 = (int)((long long)(sblk + 1) * E / nslice);
    for (int i = e0 + threadIdx.x; i < e1; i += blockDim.x) {
        int d = dst[i];
        if (d >= lo && d < hi) {
            unsigned pos = atomicAdd(&cursor[d], 1u);
            float e = __expf(t[i] * inv);
            payload[pos] = make_int2(src[i], __float_as_int(e));
        }
    }
}

__global__ void k_permute_pack(const int* __restrict__ dst, const int* __restrict__ src,
                               const float* __restrict__ t, unsigned* __restrict__ cursor,
                               int2* __restrict__ payload, int E) {
    const float inv = 1.0f / (0.5f + 1e-8f);
    int i = blockIdx.x * blockDim.x + threadIdx.x;
    int st = gridDim.x * blockDim.x;
    for (; i < E; i += st) {
        unsigned pos = atomicAdd(&cursor[dst[i]], 1u);
        float e = __expf(t[i] * inv);
        payload[pos] = make_int2(src[i], __float_as_int(e));
    }
}

__global__ __launch_bounds__(256) void k_gather4(const unsigned* __restrict__ base,
                                                 const long long* __restrict__ payload,
                                                 const uint2* __restrict__ y2,
                                                 float* __restrict__ out, int N) {
    int tid = blockIdx.x * blockDim.x + threadIdx.x;
    int lane = threadIdx.x & 63;
    int g = lane >> 4, f = lane & 15;
    int d = (tid >> 6) * 4 + g;
    if (d >= N) return;
    unsigned r0 = base[d], r1 = base[d + 1];
    int deg = (int)(r1 - r0);
    float acc0 = 0.f, acc1 = 0.f, acc2 = 0.f, acc3 = 0.f, ssum = 0.f;
    for (int it = 0; it < deg; it += 4) {
        float e[4];
        int s[4];
#pragma unroll
        for (int k2 = 0; k2 < 4; ++k2) {
            long long pl = __builtin_nontemporal_load(&payload[r0 + it + k2]);
            bool ok = (it + k2) < deg;
            e[k2] = ok ? __int_as_float((int)(pl >> 32)) : 0.f;
            s[k2] = ok ? (int)(pl & 0xFFFFFFFFll) : 0;
            ssum += e[k2];
        }
        uint2 v[4];
#pragma unroll
        for (int k2 = 0; k2 < 4; ++k2) v[k2] = y2[(size_t)s[k2] * 16 + f];
#pragma unroll
        for (int k2 = 0; k2 < 4; ++k2) {
            acc0 = fmaf(e[k2], __uint_as_float(v[k2].x << 16), acc0);
            acc1 = fmaf(e[k2], __uint_as_float(v[k2].x & 0xFFFF0000u), acc1);
            acc2 = fmaf(e[k2], __uint_as_float(v[k2].y << 16), acc2);
            acc3 = fmaf(e[k2], __uint_as_float(v[k2].y & 0xFFFF0000u), acc3);
        }
    }
    float rs = 1.0f / (ssum + 1e-16f);
    f32x4 o = {acc0 * rs, acc1 * rs, acc2 * rs, acc3 * rs};
    __builtin_nontemporal_store(o, (f32x4*)&out[(size_t)d * H + f * 4]);
}

__global__ __launch_bounds__(256) void k_gather_fb(const unsigned* __restrict__ base,
                                                   const int2* __restrict__ payload,
                                                   const float* __restrict__ x_src,
                                                   const float* __restrict__ W,
                                                   float* __restrict__ out, int N) {
    __shared__ float wt[H * H];
    for (int idx = threadIdx.x; idx < H * H; idx += blockDim.x) {
        int j = idx >> 6, k = idx & 63;
        wt[k * H + j] = W[idx];
    }
    __syncthreads();
    int lane = threadIdx.x & 63;
    int wid = (blockIdx.x * blockDim.x + threadIdx.x) >> 6;
    int nw = (gridDim.x * blockDim.x) >> 6;
    for (int d = wid; d < N; d += nw) {
        unsigned r0 = base[d], r1 = base[d + 1];
        int deg = (int)(r1 - r0);
        float acc = 0.0f, ssum = 0.0f;
        for (int c = 0; c < deg; c += 64) {
            int j = c + lane;
            int cd = min(64, deg - c);
            float e = 0.0f;
            int sidx = 0;
            if (j < deg) {
                int2 p = payload[r0 + j];
                sidx = p.x;
                e = __int_as_float(p.y);
            }
            float cs = e;
#pragma unroll
            for (int off = 32; off >= 1; off >>= 1) cs += __shfl_xor(cs, off, 64);
            ssum += cs;
            for (int q = 0; q < cd; q += 8) {
                float a[8];
                int sv[8];
                float v[8];
#pragma unroll
                for (int u = 0; u < 8; ++u) {
                    a[u] = __shfl(e, q + u, 64);
                    sv[u] = __shfl(sidx, q + u, 64);
                }
#pragma unroll
                for (int u = 0; u < 8; ++u) v[u] = x_src[(size_t)sv[u] * H + lane];
#pragma unroll
                for (int u = 0; u < 8; ++u) acc = fmaf(a[u], v[u], acc);
            }
        }
        acc *= 1.0f / (ssum + 1e-16f);
        float o = 0.0f;
#pragma unroll
        for (int k = 0; k < H; ++k) o = fmaf(__shfl(acc, k, 64), wt[k * H + lane], o);
        out[(size_t)d * H + lane] = o;
    }
}

extern "C" void kernel_launch(void* const* d_in, const int* in_sizes, int n_in,
                              void* d_out, int out_size, void* d_ws, size_t ws_size,
                              hipStream_t stream) {
    const float* x_src = (const float*)d_in[0];
    const float* W = (const float*)d_in[2];
    const int* edge_index = (const int*)d_in[3];
    const float* t = (const float*)d_in[4];

    int E = in_sizes[4];
    int N = in_sizes[1] / H;  // N_DST
    int M = in_sizes[0] / H;  // N_SRC
    const int* src = edge_index;
    const int* dst = edge_index + E;

    // head layout kept identical to R19/R20 (fallback paths depend on it)
    unsigned* base = (unsigned*)d_ws;
    unsigned* cursor = base + (size_t)N + 1;
    unsigned* bsum = cursor + N;
    unsigned* boff = bsum + 1024;
    size_t head_u32 = (size_t)(2 * N + 1) + 1024 + 1024 + 32 + 1024 + 1056 + 1056;
    size_t pay_off = (head_u32 * 4 + 15) & ~(size_t)15;
    int2* payload = (int2*)((char*)d_ws + pay_off);

    // fast-path layout
    int nchunks = (E + CH3 - 1) / CH3;
    size_t bin2_entries = (size_t)nchunks * CH3;
    unsigned* rofs = (unsigned*)((char*)d_ws + pay_off);
    unsigned* rlen = rofs + (size_t)MAXCH * 1024;
    size_t b2_off = (pay_off + (size_t)MAXCH * 1024 * 8 + 15) & ~(size_t)15;
    unsigned long long* bin2 = (unsigned long long*)((char*)d_ws + b2_off);
    size_t yf_off = b2_off + bin2_entries * 8;
    ushort* y = (ushort*)((char*)d_ws + yf_off);

    bool packable = (M < (1 << 17)) && (N < (1 << 17));
    int NB = (N + 255) >> 8;
    bool have_fast = (ws_size >= yf_off + (size_t)M * H * 2) && packable &&
                     (NB <= 1024) && (nchunks <= MAXCH);
    bool have_y_small = (ws_size >= pay_off + (size_t)E * 8 + (size_t)M * H * 2 + 32);

    int nb = (N + 1023) / 1024;
    int blocks_e = (E + 255) / 256;
    if (blocks_e > 2048) blocks_e = 2048;

    if (have_fast) {
        int xb = (M + 255) / 256;  // 16 waves x 16 rows per block
        k_prep<<<nchunks + xb, 1024, 0, stream>>>(x_src, W, y, M, dst, src, t,
                                                  bin2, rofs, rlen, E, nchunks);
        k_fuse_runs<<<NB, 1024, 0, stream>>>(rofs, rlen, bin2, (const uint4*)y,
                                             (float*)d_out, N, nchunks);
    } else if (have_y_small) {
        ushort* y2p = (ushort*)((char*)d_ws + pay_off + (size_t)E * 8);
        hipMemsetAsync(cursor, 0, (size_t)N * sizeof(unsigned), stream);
        k_hist<<<1024, 256, 0, stream>>>(dst, cursor, E);
        k_scanA<<<nb, 1024, 0, stream>>>(cursor, base, bsum, N);
        k_scanB<<<1, 1024, 0, stream>>>(bsum, boff, nb);
        k_scanC<<<512, 256, 0, stream>>>(base, cursor, boff, N, E);
        int xblocks = ((M + 15) / 16 * 64 + 255) / 256;
        k_xform_mfma<<<xblocks, 256, 0, stream>>>(x_src, W, y2p, M);
        k_permute_part<<<2048, 256, 0, stream>>>(dst, src, t, cursor, payload, E, N);
        int gblocks = (N + 15) / 16;
        k_gather4<<<gblocks, 256, 0, stream>>>(base, (const long long*)payload,
                                               (const uint2*)y2p, (float*)d_out, N);
    } else {
        hipMemsetAsync(cursor, 0, (size_t)N * sizeof(unsigned), stream);
        k_hist<<<1024, 256, 0, stream>>>(dst, cursor, E);
        k_scanA<<<nb, 1024, 0, stream>>>(cursor, base, bsum, N);
        k_scanB<<<1, 1024, 0, stream>>>(bsum, boff, nb);
        k_scanC<<<512, 256, 0, stream>>>(base, cursor, boff, N, E);
        k_permute_pack<<<blocks_e, 256, 0, stream>>>(dst, src, t, cursor, payload, E);
        k_gather_fb<<<4096, 256, 0, stream>>>(base, payload, x_src, W, (float*)d_out, N);
    }
}

// Round 22
// 73.012 us; speedup vs baseline: 1.8725x; 1.0055x over previous
//
#include <hip/hip_runtime.h>
#include <math.h>

#define H 64
#define NXCD 8
#define CH3 4096
#define CAP 4096
#define MAXCH 256

typedef __attribute__((ext_vector_type(8))) short short8;
typedef __attribute__((ext_vector_type(4))) float f32x4;

__device__ inline ushort f2bf(float f) {
    union { float f; unsigned u; } v;
    v.f = f;
    unsigned r = v.u + 0x7FFFu + ((v.u >> 16) & 1u);
    return (ushort)(r >> 16);
}

// ================= FAST PATH (2 kernels) =================

// ---------- Stage 1 (MERGED): bin chunks + xform tiles in one dispatch ----------
// Blocks [0, nchunks): chunk -> LDS bucket-sort -> static slab + run table.
// Blocks [nchunks, nchunks+xb): y(bf16) = x @ W^T via MFMA, 16 waves x 16 rows.
// CH3=4096 -> ~37KB LDS -> 4 blocks/CU (R21 was 68KB -> 2/CU).
__global__ __launch_bounds__(1024) void k_prep(const float* __restrict__ x,
                                               const float* __restrict__ W,
                                               ushort* __restrict__ y, int M,
                                               const int* __restrict__ dst,
                                               const int* __restrict__ src,
                                               const float* __restrict__ t,
                                               unsigned long long* __restrict__ bin2,
                                               unsigned* __restrict__ rofs,
                                               unsigned* __restrict__ rlen,
                                               int E, int nchunks) {
    __shared__ unsigned long long slab[CH3];
    __shared__ unsigned lcnt[1024];
    __shared__ unsigned wsum[16];
    int tid = threadIdx.x;
    if ((int)blockIdx.x < nchunks) {
        // ----- bin_runs body (verified R19/R20) -----
        int c = blockIdx.x;
        int e0 = c * CH3;
        int e1 = min(e0 + CH3, E);
        int cnt = e1 - e0;
        lcnt[tid] = 0;
        __syncthreads();
        for (int i = e0 + tid; i < e1; i += 1024) atomicAdd(&lcnt[dst[i] >> 8], 1u);
        __syncthreads();
        unsigned v = lcnt[tid];
        int lane = tid & 63, w = tid >> 6;
        unsigned xx = v;
#pragma unroll
        for (int off = 1; off < 64; off <<= 1) {
            unsigned yv = __shfl_up(xx, off, 64);
            if (lane >= off) xx += yv;
        }
        if (lane == 63) wsum[w] = xx;
        __syncthreads();
        if (tid < 16) {
            unsigned s = wsum[tid];
#pragma unroll
            for (int off = 1; off < 16; off <<= 1) {
                unsigned yv = __shfl_up(s, off, 16);
                if ((tid & 15) >= off) s += yv;
            }
            wsum[tid] = s;
        }
        __syncthreads();
        unsigned excl = ((w > 0) ? wsum[w - 1] : 0u) + xx - v;
        rofs[(size_t)c * 1024 + tid] = (unsigned)e0 + excl;
        rlen[(size_t)c * 1024 + tid] = v;
        __syncthreads();
        lcnt[tid] = excl;  // running cursor
        __syncthreads();
        const float inv = 1.0f / (0.5f + 1e-8f);
        for (int i = e0 + tid; i < e1; i += 1024) {
            int d = dst[i];
            unsigned eb = f2bf(__expf(t[i] * inv));
            unsigned long long u = ((unsigned long long)d << 33)
                                 | ((unsigned long long)src[i] << 16)
                                 | (unsigned long long)eb;
            unsigned pos = atomicAdd(&lcnt[d >> 8], 1u);
            slab[pos] = u;
        }
        __syncthreads();
        for (int j = tid; j < cnt; j += 1024) bin2[e0 + j] = slab[j];
    } else {
        // ----- xform body (verified R8), 16 waves x 16-row tiles -----
        int wid = ((int)blockIdx.x - nchunks) * 16 + (tid >> 6);
        int lane = tid & 63;
        int n0 = wid * 16;
        if (n0 >= M) return;
        int r = lane & 15, g = lane >> 4;
        short8 bfrag[4][2];
#pragma unroll
        for (int ct = 0; ct < 4; ++ct) {
#pragma unroll
            for (int kh = 0; kh < 2; ++kh) {
                const float* wp = &W[(size_t)(ct * 16 + r) * 64 + kh * 32 + g * 8];
                float4 w0 = *(const float4*)wp;
                float4 w1 = *(const float4*)(wp + 4);
                short8 bf;
                bf[0] = (short)f2bf(w0.x); bf[1] = (short)f2bf(w0.y);
                bf[2] = (short)f2bf(w0.z); bf[3] = (short)f2bf(w0.w);
                bf[4] = (short)f2bf(w1.x); bf[5] = (short)f2bf(w1.y);
                bf[6] = (short)f2bf(w1.z); bf[7] = (short)f2bf(w1.w);
                bfrag[ct][kh] = bf;
            }
        }
        int xr = n0 + r;
        if (xr >= M) xr = M - 1;
        const float* xp = &x[(size_t)xr * 64 + g * 8];
        short8 afrag[2];
#pragma unroll
        for (int kh = 0; kh < 2; ++kh) {
            float4 a0 = *(const float4*)(xp + kh * 32);
            float4 a1 = *(const float4*)(xp + kh * 32 + 4);
            short8 af;
            af[0] = (short)f2bf(a0.x); af[1] = (short)f2bf(a0.y);
            af[2] = (short)f2bf(a0.z); af[3] = (short)f2bf(a0.w);
            af[4] = (short)f2bf(a1.x); af[5] = (short)f2bf(a1.y);
            af[6] = (short)f2bf(a1.z); af[7] = (short)f2bf(a1.w);
            afrag[kh] = af;
        }
#pragma unroll
        for (int ct = 0; ct < 4; ++ct) {
            f32x4 acc = {0.f, 0.f, 0.f, 0.f};
            acc = __builtin_amdgcn_mfma_f32_16x16x32_bf16(afrag[0], bfrag[ct][0], acc, 0, 0, 0);
            acc = __builtin_amdgcn_mfma_f32_16x16x32_bf16(afrag[1], bfrag[ct][1], acc, 0, 0, 0);
#pragma unroll
            for (int q = 0; q < 4; ++q) {
                int row = n0 + g * 4 + q;
                if (row < M) y[(size_t)row * 64 + ct * 16 + r] = f2bf(acc[q]);
            }
        }
    }
}

// ---------- Stage 2 (FUSED): run-table -> LDS CSR slab -> direct gather ----------
__global__ __launch_bounds__(1024) void k_fuse_runs(const unsigned* __restrict__ rofs,
                                                    const unsigned* __restrict__ rlen,
                                                    const unsigned long long* __restrict__ bin2,
                                                    const uint4* __restrict__ y4,
                                                    float* __restrict__ out,
                                                    int N, int nchunks) {
    __shared__ long long sPay[CAP];
    __shared__ unsigned lcnt[256];
    __shared__ unsigned lrel[257];
    __shared__ unsigned wsum[4];
    __shared__ unsigned rofsL[MAXCH];
    __shared__ unsigned rlenL[MAXCH];
    __shared__ unsigned rcum[MAXCH + 1];
    int b = blockIdx.x;
    int d0 = b << 8;
    int d1 = min(d0 + 256, N);
    int nd = d1 - d0;
    int tid = threadIdx.x;
    if (tid < nchunks) {
        rofsL[tid] = rofs[(size_t)tid * 1024 + b];
        rlenL[tid] = rlen[(size_t)tid * 1024 + b];
    }
    if (tid < 256) lcnt[tid] = 0;
    __syncthreads();
    if (tid == 0) {
        unsigned s = 0;
        for (int c = 0; c < nchunks; ++c) { rcum[c] = s; s += rlenL[c]; }
        rcum[nchunks] = s;
    }
    __syncthreads();
    int cnt = (int)rcum[nchunks];

    if (cnt > CAP) {
        // slow path (statistically never; deterministic): per-dst global walk
        int grp = tid >> 3, f = tid & 7;
        for (int ld = grp; ld < nd; ld += 128) {
            float acc[8] = {0.f, 0.f, 0.f, 0.f, 0.f, 0.f, 0.f, 0.f};
            float ssum = 0.f;
            for (int c = 0; c < nchunks; ++c) {
                unsigned ro = rofsL[c];
                int rl = (int)rlenL[c];
                for (int j = 0; j < rl; ++j) {
                    unsigned long long u = bin2[ro + j];
                    if ((int)(u >> 33) - d0 == ld) {
                        float e = __uint_as_float((unsigned)(u & 0xFFFFu) << 16);
                        int s = (int)((u >> 16) & 0x1FFFF);
                        ssum += e;
                        uint4 v = y4[(size_t)s * 8 + f];
                        acc[0] = fmaf(e, __uint_as_float(v.x << 16), acc[0]);
                        acc[1] = fmaf(e, __uint_as_float(v.x & 0xFFFF0000u), acc[1]);
                        acc[2] = fmaf(e, __uint_as_float(v.y << 16), acc[2]);
                        acc[3] = fmaf(e, __uint_as_float(v.y & 0xFFFF0000u), acc[3]);
                        acc[4] = fmaf(e, __uint_as_float(v.z << 16), acc[4]);
                        acc[5] = fmaf(e, __uint_as_float(v.z & 0xFFFF0000u), acc[5]);
                        acc[6] = fmaf(e, __uint_as_float(v.w << 16), acc[6]);
                        acc[7] = fmaf(e, __uint_as_float(v.w & 0xFFFF0000u), acc[7]);
                    }
                }
            }
            float rs = 1.0f / (ssum + 1e-16f);
            f32x4 o0 = {acc[0] * rs, acc[1] * rs, acc[2] * rs, acc[3] * rs};
            f32x4 o1 = {acc[4] * rs, acc[5] * rs, acc[6] * rs, acc[7] * rs};
            float* op = &out[(size_t)(d0 + ld) * H + f * 8];
            __builtin_nontemporal_store(o0, (f32x4*)op);
            __builtin_nontemporal_store(o1, (f32x4*)(op + 4));
        }
        return;
    }

    // Phase A1: count local dsts (flat index -> chunk via LDS binary search)
    for (int k = tid; k < cnt; k += 1024) {
        int lo = 0, hi = nchunks - 1;
        while (lo < hi) { int mid = (lo + hi + 1) >> 1; if ((int)rcum[mid] <= k) lo = mid; else hi = mid - 1; }
        unsigned long long u = bin2[rofsL[lo] + (unsigned)(k - (int)rcum[lo])];
        atomicAdd(&lcnt[(int)(u >> 33) - d0], 1u);
    }
    __syncthreads();
    // Phase A2: exclusive scan of 256 counters
    if (tid < 256) {
        unsigned v = lcnt[tid];
        int lane = tid & 63, w = tid >> 6;
        unsigned x = v;
#pragma unroll
        for (int off = 1; off < 64; off <<= 1) {
            unsigned y = __shfl_up(x, off, 64);
            if (lane >= off) x += y;
        }
        if (lane == 63) wsum[w] = x;
        __syncthreads();
        if (tid == 0) {
            unsigned s = 0;
#pragma unroll
            for (int k = 0; k < 4; ++k) { unsigned tq = wsum[k]; wsum[k] = s; s += tq; }
        }
        __syncthreads();
        unsigned excl = wsum[w] + x - v;
        lrel[tid] = excl;
        lcnt[tid] = excl;
        if (tid == 0) lrel[256] = (unsigned)cnt;
    } else {
        __syncthreads();
        __syncthreads();
    }
    __syncthreads();
    // Phase A3: scatter entries into LDS slab (second read is L2-hot)
    for (int k = tid; k < cnt; k += 1024) {
        int lo = 0, hi = nchunks - 1;
        while (lo < hi) { int mid = (lo + hi + 1) >> 1; if ((int)rcum[mid] <= k) lo = mid; else hi = mid - 1; }
        unsigned long long u = bin2[rofsL[lo] + (unsigned)(k - (int)rcum[lo])];
        int d = (int)(u >> 33);
        int s = (int)((u >> 16) & 0x1FFFF);
        unsigned ef = (unsigned)(u & 0xFFFFu) << 16;
        unsigned lpos = atomicAdd(&lcnt[d - d0], 1u);
        sPay[lpos] = ((long long)(int)ef << 32) | (unsigned)s;
    }
    __syncthreads();
    // Phase B: gather. 128 groups of 8 lanes, 2 rounds over 256 dsts.
    int g = tid >> 3, f = tid & 7;
#pragma unroll
    for (int round = 0; round < 2; ++round) {
        int ld = round * 128 + g;
        if (ld >= nd) continue;
        int r0 = (int)lrel[ld];
        int r1 = (int)lrel[ld + 1];
        int deg = r1 - r0;
        float acc[8] = {0.f, 0.f, 0.f, 0.f, 0.f, 0.f, 0.f, 0.f};
        float ssum = 0.f;
        for (int it = 0; it < deg; it += 4) {
            float e[4];
            int s[4];
#pragma unroll
            for (int k2 = 0; k2 < 4; ++k2) {
                int pos = r0 + it + k2;
                bool ok = (it + k2) < deg;
                long long pl = sPay[ok ? pos : r0];
                e[k2] = ok ? __int_as_float((int)(pl >> 32)) : 0.f;
                s[k2] = ok ? (int)(pl & 0xFFFFFFFFll) : 0;
                ssum += e[k2];
            }
            uint4 v[4];
#pragma unroll
            for (int k2 = 0; k2 < 4; ++k2) v[k2] = y4[(size_t)s[k2] * 8 + f];
#pragma unroll
            for (int k2 = 0; k2 < 4; ++k2) {
                acc[0] = fmaf(e[k2], __uint_as_float(v[k2].x << 16), acc[0]);
                acc[1] = fmaf(e[k2], __uint_as_float(v[k2].x & 0xFFFF0000u), acc[1]);
                acc[2] = fmaf(e[k2], __uint_as_float(v[k2].y << 16), acc[2]);
                acc[3] = fmaf(e[k2], __uint_as_float(v[k2].y & 0xFFFF0000u), acc[3]);
                acc[4] = fmaf(e[k2], __uint_as_float(v[k2].z << 16), acc[4]);
                acc[5] = fmaf(e[k2], __uint_as_float(v[k2].z & 0xFFFF0000u), acc[5]);
                acc[6] = fmaf(e[k2], __uint_as_float(v[k2].w << 16), acc[6]);
                acc[7] = fmaf(e[k2], __uint_as_float(v[k2].w & 0xFFFF0000u), acc[7]);
            }
        }
        float rs = 1.0f / (ssum + 1e-16f);
        f32x4 o0 = {acc[0] * rs, acc[1] * rs, acc[2] * rs, acc[3] * rs};
        f32x4 o1 = {acc[4] * rs, acc[5] * rs, acc[6] * rs, acc[7] * rs};
        float* op = &out[(size_t)(d0 + ld) * H + f * 8];
        __builtin_nontemporal_store(o0, (f32x4*)op);
        __builtin_nontemporal_store(o1, (f32x4*)(op + 4));
    }
}

// ---------- Standalone xform (fallback paths) ----------
__global__ __launch_bounds__(256) void k_xform_mfma(const float* __restrict__ x,
                                                    const float* __restrict__ W,
                                                    ushort* __restrict__ y, int M) {
    int wid = (blockIdx.x * blockDim.x + threadIdx.x) >> 6;
    int lane = threadIdx.x & 63;
    int n0 = wid * 16;
    if (n0 >= M) return;
    int r = lane & 15, g = lane >> 4;
    short8 bfrag[4][2];
#pragma unroll
    for (int ct = 0; ct < 4; ++ct) {
#pragma unroll
        for (int kh = 0; kh < 2; ++kh) {
            const float* wp = &W[(size_t)(ct * 16 + r) * 64 + kh * 32 + g * 8];
            float4 w0 = *(const float4*)wp;
            float4 w1 = *(const float4*)(wp + 4);
            short8 bf;
            bf[0] = (short)f2bf(w0.x); bf[1] = (short)f2bf(w0.y);
            bf[2] = (short)f2bf(w0.z); bf[3] = (short)f2bf(w0.w);
            bf[4] = (short)f2bf(w1.x); bf[5] = (short)f2bf(w1.y);
            bf[6] = (short)f2bf(w1.z); bf[7] = (short)f2bf(w1.w);
            bfrag[ct][kh] = bf;
        }
    }
    int xr = n0 + r;
    if (xr >= M) xr = M - 1;
    const float* xp = &x[(size_t)xr * 64 + g * 8];
    short8 afrag[2];
#pragma unroll
    for (int kh = 0; kh < 2; ++kh) {
        float4 a0 = *(const float4*)(xp + kh * 32);
        float4 a1 = *(const float4*)(xp + kh * 32 + 4);
        short8 af;
        af[0] = (short)f2bf(a0.x); af[1] = (short)f2bf(a0.y);
        af[2] = (short)f2bf(a0.z); af[3] = (short)f2bf(a0.w);
        af[4] = (short)f2bf(a1.x); af[5] = (short)f2bf(a1.y);
        af[6] = (short)f2bf(a1.z); af[7] = (short)f2bf(a1.w);
        afrag[kh] = af;
    }
#pragma unroll
    for (int ct = 0; ct < 4; ++ct) {
        f32x4 acc = {0.f, 0.f, 0.f, 0.f};
        acc = __builtin_amdgcn_mfma_f32_16x16x32_bf16(afrag[0], bfrag[ct][0], acc, 0, 0, 0);
        acc = __builtin_amdgcn_mfma_f32_16x16x32_bf16(afrag[1], bfrag[ct][1], acc, 0, 0, 0);
#pragma unroll
        for (int q = 0; q < 4; ++q) {
            int row = n0 + g * 4 + q;
            if (row < M) y[(size_t)row * 64 + ct * 16 + r] = f2bf(acc[q]);
        }
    }
}

// ================= FALLBACK PATH (R10-proven) =================

__global__ void k_hist(const int* __restrict__ dst, unsigned* __restrict__ cnt, int E) {
    int i = blockIdx.x * blockDim.x + threadIdx.x;
    int st = gridDim.x * blockDim.x;
    int E4 = E >> 2;
    const int4* d4 = (const int4*)dst;
    for (int k = i; k < E4; k += st) {
        int4 v = d4[k];
        atomicAdd(&cnt[v.x], 1u);
        atomicAdd(&cnt[v.y], 1u);
        atomicAdd(&cnt[v.z], 1u);
        atomicAdd(&cnt[v.w], 1u);
    }
    for (int k = (E4 << 2) + i; k < E; k += st) atomicAdd(&cnt[dst[k]], 1u);
}

__global__ __launch_bounds__(1024) void k_scanA(const unsigned* __restrict__ cnt,
                                                unsigned* __restrict__ base,
                                                unsigned* __restrict__ bsum, int N) {
    __shared__ unsigned wsum[16];
    int i = blockIdx.x * 1024 + threadIdx.x;
    unsigned v = (i < N) ? cnt[i] : 0u;
    int lane = threadIdx.x & 63, w = threadIdx.x >> 6;
    unsigned x = v;
#pragma unroll
    for (int off = 1; off < 64; off <<= 1) {
        unsigned y = __shfl_up(x, off, 64);
        if (lane >= off) x += y;
    }
    if (lane == 63) wsum[w] = x;
    __syncthreads();
    if (threadIdx.x < 16) {
        unsigned s = wsum[threadIdx.x];
#pragma unroll
        for (int off = 1; off < 16; off <<= 1) {
            unsigned y = __shfl_up(s, off, 16);
            if ((threadIdx.x & 15) >= off) s += y;
        }
        wsum[threadIdx.x] = s;
    }
    __syncthreads();
    unsigned wbase = (w > 0) ? wsum[w - 1] : 0u;
    if (i < N) base[i] = wbase + x - v;
    if (threadIdx.x == 1023) bsum[blockIdx.x] = wsum[15];
}

__global__ __launch_bounds__(1024) void k_scanB(const unsigned* __restrict__ bsum,
                                                unsigned* __restrict__ boff, int nb) {
    __shared__ unsigned wsum[16];
    int i = threadIdx.x;
    unsigned v = (i < nb) ? bsum[i] : 0u;
    int lane = i & 63, w = i >> 6;
    unsigned x = v;
#pragma unroll
    for (int off = 1; off < 64; off <<= 1) {
        unsigned y = __shfl_up(x, off, 64);
        if (lane >= off) x += y;
    }
    if (lane == 63) wsum[w] = x;
    __syncthreads();
    if (i < 16) {
        unsigned s = wsum[i];
#pragma unroll
        for (int off = 1; off < 16; off <<= 1) {
            unsigned y = __shfl_up(s, off, 16);
            if ((i & 15) >= off) s += y;
        }
        wsum[i] = s;
    }
    __syncthreads();
    unsigned wbase = (w > 0) ? wsum[w - 1] : 0u;
    if (i < nb) boff[i] = wbase + x - v;
}

__global__ void k_scanC(unsigned* __restrict__ base, unsigned* __restrict__ cursor,
                        const unsigned* __restrict__ boff, int N, int E) {
    int i = blockIdx.x * blockDim.x + threadIdx.x;
    int st = gridDim.x * blockDim.x;
    for (; i < N; i += st) {
        unsigned b = base[i] + boff[i >> 10];
        base[i] = b;
        cursor[i] = b;
    }
    if (blockIdx.x == 0 && threadIdx.x == 0) base[N] = (unsigned)E;
}

__global__ void k_permute_part(const int* __restrict__ dst, const int* __restrict__ src,
                               const float* __restrict__ t, unsigned* __restrict__ cursor,
                               int2* __restrict__ payload, int E, int N) {
    const float inv = 1.0f / (0.5f + 1e-8f);
    int part = blockIdx.x & (NXCD - 1);
    int nslice = gridDim.x >> 3;
    int sblk = blockIdx.x >> 3;
    int lo = (int)((long long)part * N / NXCD);
    int hi = (int)((long long)(part + 1) * N / NXCD);
    int e0 = (int)((long long)sblk * E / nslice);
    int e1 = (int)((long long)(sblk + 1) * E / nslice);
    for (int i = e0 + threadIdx.x; i < e1; i += blockDim.x) {
        int d = dst[i];
        if (d >= lo && d < hi) {
            unsigned pos = atomicAdd(&cursor[d], 1u);
            float e = __expf(t[i] * inv);
            payload[pos] = make_int2(src[i], __float_as_int(e));
        }
    }
}

__global__ void k_permute_pack(const int* __restrict__ dst, const int* __restrict__ src,
                               const float* __restrict__ t, unsigned* __restrict__ cursor,
                               int2* __restrict__ payload, int E) {
    const float inv = 1.0f / (0.5f + 1e-8f);
    int i = blockIdx.x * blockDim.x + threadIdx.x;
    int st = gridDim.x * blockDim.x;
    for (; i < E; i += st) {
        unsigned pos = atomicAdd(&cursor[dst[i]], 1u);
        float e = __expf(t[i] * inv);
        payload[pos] = make_int2(src[i], __float_as_int(e));
    }
}

__global__ __launch_bounds__(256) void k_gather4(const unsigned* __restrict__ base,
                                                 const long long* __restrict__ payload,
                                                 const uint2* __restrict__ y2,
                                                 float* __restrict__ out, int N) {
    int tid = blockIdx.x * blockDim.x + threadIdx.x;
    int lane = threadIdx.x & 63;
    int g = lane >> 4, f = lane & 15;
    int d = (tid >> 6) * 4 + g;
    if (d >= N) return;
    unsigned r0 = base[d], r1 = base[d + 1];
    int deg = (int)(r1 - r0);
    float acc0 = 0.f, acc1 = 0.f, acc2 = 0.f, acc3 = 0.f, ssum = 0.f;
    for (int it = 0; it < deg; it += 4) {
        float e[4];
        int s[4];
#pragma unroll
        for (int k2 = 0; k2 < 4; ++k2) {
            long long pl = __builtin_nontemporal_load(&payload[r0 + it + k2]);
            bool ok = (it + k2) < deg;
            e[k2] = ok ? __int_as_float((int)(pl >> 32)) : 0.f;
            s[k2] = ok ? (int)(pl & 0xFFFFFFFFll) : 0;
            ssum += e[k2];
        }
        uint2 v[4];
#pragma unroll
        for (int k2 = 0; k2 < 4; ++k2) v[k2] = y2[(size_t)s[k2] * 16 + f];
#pragma unroll
        for (int k2 = 0; k2 < 4; ++k2) {
            acc0 = fmaf(e[k2], __uint_as_float(v[k2].x << 16), acc0);
            acc1 = fmaf(e[k2], __uint_as_float(v[k2].x & 0xFFFF0000u), acc1);
            acc2 = fmaf(e[k2], __uint_as_float(v[k2].y << 16), acc2);
            acc3 = fmaf(e[k2], __uint_as_float(v[k2].y & 0xFFFF0000u), acc3);
        }
    }
    float rs = 1.0f / (ssum + 1e-16f);
    f32x4 o = {acc0 * rs, acc1 * rs, acc2 * rs, acc3 * rs};
    __builtin_nontemporal_store(o, (f32x4*)&out[(size_t)d * H + f * 4]);
}

__global__ __launch_bounds__(256) void k_gather_fb(const unsigned* __restrict__ base,
                                                   const int2* __restrict__ payload,
                                                   const float* __restrict__ x_src,
                                                   const float* __restrict__ W,
                                                   float* __restrict__ out, int N) {
    __shared__ float wt[H * H];
    for (int idx = threadIdx.x; idx < H * H; idx += blockDim.x) {
        int j = idx >> 6, k = idx & 63;
        wt[k * H + j] = W[idx];
    }
    __syncthreads();
    int lane = threadIdx.x & 63;
    int wid = (blockIdx.x * blockDim.x + threadIdx.x) >> 6;
    int nw = (gridDim.x * blockDim.x) >> 6;
    for (int d = wid; d < N; d += nw) {
        unsigned r0 = base[d], r1 = base[d + 1];
        int deg = (int)(r1 - r0);
        float acc = 0.0f, ssum = 0.0f;
        for (int c = 0; c < deg; c += 64) {
            int j = c + lane;
            int cd = min(64, deg - c);
            float e = 0.0f;
            int sidx = 0;
            if (j < deg) {
                int2 p = payload[r0 + j];
                sidx = p.x;
                e = __int_as_float(p.y);
            }
            float cs = e;
#pragma unroll
            for (int off = 32; off >= 1; off >>= 1) cs += __shfl_xor(cs, off, 64);
            ssum += cs;
            for (int q = 0; q < cd; q += 8) {
                float a[8];
                int sv[8];
                float v[8];
#pragma unroll
                for (int u = 0; u < 8; ++u) {
                    a[u] = __shfl(e, q + u, 64);
                    sv[u] = __shfl(sidx, q + u, 64);
                }
#pragma unroll
                for (int u = 0; u < 8; ++u) v[u] = x_src[(size_t)sv[u] * H + lane];
#pragma unroll
                for (int u = 0; u < 8; ++u) acc = fmaf(a[u], v[u], acc);
            }
        }
        acc *= 1.0f / (ssum + 1e-16f);
        float o = 0.0f;
#pragma unroll
        for (int k = 0; k < H; ++k) o = fmaf(__shfl(acc, k, 64), wt[k * H + lane], o);
        out[(size_t)d * H + lane] = o;
    }
}

extern "C" void kernel_launch(void* const* d_in, const int* in_sizes, int n_in,
                              void* d_out, int out_size, void* d_ws, size_t ws_size,
                              hipStream_t stream) {
    const float* x_src = (const float*)d_in[0];
    const float* W = (const float*)d_in[2];
    const int* edge_index = (const int*)d_in[3];
    const float* t = (const float*)d_in[4];

    int E = in_sizes[4];
    int N = in_sizes[1] / H;  // N_DST
    int M = in_sizes[0] / H;  // N_SRC
    const int* src = edge_index;
    const int* dst = edge_index + E;

    // head layout kept identical to R19/R20 (fallback paths depend on it)
    unsigned* base = (unsigned*)d_ws;
    unsigned* cursor = base + (size_t)N + 1;
    unsigned* bsum = cursor + N;
    unsigned* boff = bsum + 1024;
    size_t head_u32 = (size_t)(2 * N + 1) + 1024 + 1024 + 32 + 1024 + 1056 + 1056;
    size_t pay_off = (head_u32 * 4 + 15) & ~(size_t)15;
    int2* payload = (int2*)((char*)d_ws + pay_off);

    // fast-path layout
    int nchunks = (E + CH3 - 1) / CH3;
    size_t bin2_entries = (size_t)nchunks * CH3;
    unsigned* rofs = (unsigned*)((char*)d_ws + pay_off);
    unsigned* rlen = rofs + (size_t)MAXCH * 1024;
    size_t b2_off = (pay_off + (size_t)MAXCH * 1024 * 8 + 15) & ~(size_t)15;
    unsigned long long* bin2 = (unsigned long long*)((char*)d_ws + b2_off);
    size_t yf_off = b2_off + bin2_entries * 8;
    ushort* y = (ushort*)((char*)d_ws + yf_off);

    bool packable = (M < (1 << 17)) && (N < (1 << 17));
    int NB = (N + 255) >> 8;
    bool have_fast = (ws_size >= yf_off + (size_t)M * H * 2) && packable &&
                     (NB <= 1024) && (nchunks <= MAXCH);
    bool have_y_small = (ws_size >= pay_off + (size_t)E * 8 + (size_t)M * H * 2 + 32);

    int nb = (N + 1023) / 1024;
    int blocks_e = (E + 255) / 256;
    if (blocks_e > 2048) blocks_e = 2048;

    if (have_fast) {
        int xb = (M + 255) / 256;  // 16 waves x 16 rows per block
        k_prep<<<nchunks + xb, 1024, 0, stream>>>(x_src, W, y, M, dst, src, t,
                                                  bin2, rofs, rlen, E, nchunks);
        k_fuse_runs<<<NB, 1024, 0, stream>>>(rofs, rlen, bin2, (const uint4*)y,
                                             (float*)d_out, N, nchunks);
    } else if (have_y_small) {
        ushort* y2p = (ushort*)((char*)d_ws + pay_off + (size_t)E * 8);
        hipMemsetAsync(cursor, 0, (size_t)N * sizeof(unsigned), stream);
        k_hist<<<1024, 256, 0, stream>>>(dst, cursor, E);
        k_scanA<<<nb, 1024, 0, stream>>>(cursor, base, bsum, N);
        k_scanB<<<1, 1024, 0, stream>>>(bsum, boff, nb);
        k_scanC<<<512, 256, 0, stream>>>(base, cursor, boff, N, E);
        int xblocks = ((M + 15) / 16 * 64 + 255) / 256;
        k_xform_mfma<<<xblocks, 256, 0, stream>>>(x_src, W, y2p, M);
        k_permute_part<<<2048, 256, 0, stream>>>(dst, src, t, cursor, payload, E, N);
        int gblocks = (N + 15) / 16;
        k_gather4<<<gblocks, 256, 0, stream>>>(base, (const long long*)payload,
                                               (const uint2*)y2p, (float*)d_out, N);
    } else {
        hipMemsetAsync(cursor, 0, (size_t)N * sizeof(unsigned), stream);
        k_hist<<<1024, 256, 0, stream>>>(dst, cursor, E);
        k_scanA<<<nb, 1024, 0, stream>>>(cursor, base, bsum, N);
        k_scanB<<<1, 1024, 0, stream>>>(bsum, boff, nb);
        k_scanC<<<512, 256, 0, stream>>>(base, cursor, boff, N, E);
        k_permute_pack<<<blocks_e, 256, 0, stream>>>(dst, src, t, cursor, payload, E);
        k_gather_fb<<<4096, 256, 0, stream>>>(base, payload, x_src, W, (float*)d_out, N);
    }
}